// Round 1
// baseline (8850.594 us; speedup 1.0000x reference)
//
#include <hip/hip_runtime.h>
#include <hip/hip_bf16.h>

#define N_NODES   100000
#define N_EDGES   800000
#define NUM_GRAPHS 512
#define IN_DIM    16
#define HID       64
#define MLP_H     32
#define EPS       1e-5f
#define TPB       256

// -------------------- helpers --------------------
__device__ __forceinline__ float wsum(float v) {
  v += __shfl_xor(v, 1, 64);
  v += __shfl_xor(v, 2, 64);
  v += __shfl_xor(v, 4, 64);
  v += __shfl_xor(v, 8, 64);
  v += __shfl_xor(v, 16, 64);
  v += __shfl_xor(v, 32, 64);
  return v;
}

// -------------------- kernels --------------------
__global__ __launch_bounds__(TPB) void k_deg(const int* __restrict__ ei, int* __restrict__ deg) {
  int e = blockIdx.x * TPB + threadIdx.x;
  if (e < N_EDGES) atomicAdd(&deg[ei[N_EDGES + e]], 1);
}

__global__ __launch_bounds__(TPB) void k_lin_in(const float* __restrict__ x,
                                                const float* __restrict__ w,
                                                const float* __restrict__ b,
                                                float* __restrict__ h) {
  int i = blockIdx.x * TPB + threadIdx.x;
  if (i >= N_NODES) return;
  float xi[IN_DIM];
  const float4* xp = reinterpret_cast<const float4*>(x + (size_t)i * IN_DIM);
#pragma unroll
  for (int q = 0; q < 4; ++q) {
    float4 v = xp[q];
    xi[4*q] = v.x; xi[4*q+1] = v.y; xi[4*q+2] = v.z; xi[4*q+3] = v.w;
  }
  float4* hp = reinterpret_cast<float4*>(h + (size_t)i * HID);
#pragma unroll
  for (int j4 = 0; j4 < HID/4; ++j4) {
    float o[4];
#pragma unroll
    for (int c = 0; c < 4; ++c) {
      int j = j4*4 + c;
      float acc = b[j];
#pragma unroll
      for (int k = 0; k < IN_DIM; ++k) acc += xi[k] * w[k*HID + j];
      o[c] = acc;
    }
    float4 ov = {o[0], o[1], o[2], o[3]};
    hp[j4] = ov;
  }
}

// msg stage 1: z1[e] = [h[dst], h[src], ea] @ w1 + b1 ; accumulate stats(sum,sumsq) of z1
__global__ __launch_bounds__(TPB) void k_msg1(const float* __restrict__ h,
                                              const int* __restrict__ ei,
                                              const float* __restrict__ ea,
                                              const float* __restrict__ w1,
                                              const float* __restrict__ b1,
                                              float* __restrict__ z1,
                                              float* __restrict__ gstat) {
  int e = blockIdx.x * TPB + threadIdx.x;   // N_EDGES divisible by TPB: no tail
  int src = ei[e];
  int dst = ei[N_EDGES + e];
  float att = ea[e];
  float acc[MLP_H];
#pragma unroll
  for (int j = 0; j < MLP_H; ++j) acc[j] = b1[j] + att * w1[128*MLP_H + j];
  const float4* hd = reinterpret_cast<const float4*>(h + (size_t)dst * HID);
  const float4* hs = reinterpret_cast<const float4*>(h + (size_t)src * HID);
#pragma unroll 2
  for (int k4 = 0; k4 < 16; ++k4) {
    float4 a = hd[k4];
    const float* wr = w1 + (k4*4)*MLP_H;
#pragma unroll
    for (int j = 0; j < MLP_H; ++j)
      acc[j] += a.x*wr[j] + a.y*wr[MLP_H+j] + a.z*wr[2*MLP_H+j] + a.w*wr[3*MLP_H+j];
  }
#pragma unroll 2
  for (int k4 = 0; k4 < 16; ++k4) {
    float4 a = hs[k4];
    const float* wr = w1 + (64 + k4*4)*MLP_H;
#pragma unroll
    for (int j = 0; j < MLP_H; ++j)
      acc[j] += a.x*wr[j] + a.y*wr[MLP_H+j] + a.z*wr[2*MLP_H+j] + a.w*wr[3*MLP_H+j];
  }
  float4* zp = reinterpret_cast<float4*>(z1 + (size_t)e * MLP_H);
#pragma unroll
  for (int q = 0; q < MLP_H/4; ++q) {
    float4 o = {acc[4*q], acc[4*q+1], acc[4*q+2], acc[4*q+3]};
    zp[q] = o;
  }
  // stats: wave butterflies; lane j keeps wave-total for feature j
  int lane = threadIdx.x & 63;
  float msumv = 0.f, msqv = 0.f;
#pragma unroll
  for (int j = 0; j < MLP_H; ++j) {
    float s = wsum(acc[j]);
    float q = wsum(acc[j]*acc[j]);
    if (lane == j) { msumv = s; msqv = q; }
  }
  __shared__ float sred[4][2*MLP_H];
  int w = threadIdx.x >> 6;
  if (lane < MLP_H) { sred[w][lane] = msumv; sred[w][MLP_H+lane] = msqv; }
  __syncthreads();
  int t = threadIdx.x;
  if (t < 2*MLP_H)
    unsafeAtomicAdd(&gstat[t], sred[0][t]+sred[1][t]+sred[2][t]+sred[3][t]);
}

// msg stage 2 + scatter: m1 = relu(a1*z1+c1); t = relu(m1@w2+b2);
// agg[dst] += t (pre-BN2; BN2 affine folded later); stats(sum,sumsq) of t
__global__ __launch_bounds__(TPB) void k_msg2_scatter(const float* __restrict__ z1,
                                                      const int* __restrict__ ei,
                                                      const float* __restrict__ coef1, // a1[32]|c1[32]
                                                      const float* __restrict__ w2,
                                                      const float* __restrict__ b2,
                                                      float* __restrict__ agg,
                                                      float* __restrict__ gstat) {
  int e = blockIdx.x * TPB + threadIdx.x;
  int dst = ei[N_EDGES + e];
  float m1[MLP_H];
  const float4* zp = reinterpret_cast<const float4*>(z1 + (size_t)e * MLP_H);
#pragma unroll
  for (int q = 0; q < MLP_H/4; ++q) {
    float4 z = zp[q];
    int k = 4*q;
    m1[k]   = fmaxf(coef1[k]  *z.x + coef1[MLP_H+k],   0.f);
    m1[k+1] = fmaxf(coef1[k+1]*z.y + coef1[MLP_H+k+1], 0.f);
    m1[k+2] = fmaxf(coef1[k+2]*z.z + coef1[MLP_H+k+2], 0.f);
    m1[k+3] = fmaxf(coef1[k+3]*z.w + coef1[MLP_H+k+3], 0.f);
  }
  float* ap = agg + (size_t)dst * HID;
  int lane = threadIdx.x & 63;
  float msumv = 0.f, msqv = 0.f;
#pragma unroll 4
  for (int j = 0; j < HID; ++j) {
    float v = b2[j];
#pragma unroll
    for (int k = 0; k < MLP_H; ++k) v += m1[k] * w2[k*HID + j];
    v = fmaxf(v, 0.f);
    unsafeAtomicAdd(&ap[j], v);
    float s = wsum(v);
    float q = wsum(v*v);
    if (lane == j) { msumv = s; msqv = q; }
  }
  __shared__ float sred[4][2*HID];
  int w = threadIdx.x >> 6;
  sred[w][lane] = msumv; sred[w][HID+lane] = msqv;
  __syncthreads();
  int t = threadIdx.x;
  if (t < 2*HID)
    unsafeAtomicAdd(&gstat[t], sred[0][t]+sred[1][t]+sred[2][t]+sred[3][t]);
}

// update stage 1: u_in = [h, a2*agg+c2*deg]; zu1 = u_in @ w1 + b1; stats of zu1
__global__ __launch_bounds__(TPB) void k_upd1(const float* __restrict__ h,
                                              const float* __restrict__ agg,
                                              const int* __restrict__ deg,
                                              const float* __restrict__ coef2, // a2[64]|c2[64]
                                              const float* __restrict__ w1,
                                              const float* __restrict__ b1,
                                              float* __restrict__ zu1,
                                              float* __restrict__ gstat) {
  int i = blockIdx.x * TPB + threadIdx.x;
  bool valid = i < N_NODES;
  float acc[MLP_H];
#pragma unroll
  for (int j = 0; j < MLP_H; ++j) acc[j] = 0.f;
  if (valid) {
#pragma unroll
    for (int j = 0; j < MLP_H; ++j) acc[j] = b1[j];
    const float4* hp = reinterpret_cast<const float4*>(h + (size_t)i * HID);
#pragma unroll 2
    for (int k4 = 0; k4 < 16; ++k4) {
      float4 a = hp[k4];
      const float* wr = w1 + (k4*4)*MLP_H;
#pragma unroll
      for (int j = 0; j < MLP_H; ++j)
        acc[j] += a.x*wr[j] + a.y*wr[MLP_H+j] + a.z*wr[2*MLP_H+j] + a.w*wr[3*MLP_H+j];
    }
    float degf = (float)deg[i];
    const float4* ap = reinterpret_cast<const float4*>(agg + (size_t)i * HID);
#pragma unroll 2
    for (int k4 = 0; k4 < 16; ++k4) {
      float4 g4 = ap[k4];
      int k = k4*4;
      float a0 = coef2[k]  *g4.x + coef2[HID+k]  *degf;
      float a1 = coef2[k+1]*g4.y + coef2[HID+k+1]*degf;
      float a2 = coef2[k+2]*g4.z + coef2[HID+k+2]*degf;
      float a3 = coef2[k+3]*g4.w + coef2[HID+k+3]*degf;
      const float* wr = w1 + (64+k)*MLP_H;
#pragma unroll
      for (int j = 0; j < MLP_H; ++j)
        acc[j] += a0*wr[j] + a1*wr[MLP_H+j] + a2*wr[2*MLP_H+j] + a3*wr[3*MLP_H+j];
    }
    float4* zp = reinterpret_cast<float4*>(zu1 + (size_t)i * MLP_H);
#pragma unroll
    for (int q = 0; q < MLP_H/4; ++q) {
      float4 o = {acc[4*q], acc[4*q+1], acc[4*q+2], acc[4*q+3]};
      zp[q] = o;
    }
  }
  int lane = threadIdx.x & 63;
  float msumv = 0.f, msqv = 0.f;
#pragma unroll
  for (int j = 0; j < MLP_H; ++j) {
    float s = wsum(acc[j]);
    float q = wsum(acc[j]*acc[j]);
    if (lane == j) { msumv = s; msqv = q; }
  }
  __shared__ float sred[4][2*MLP_H];
  int w = threadIdx.x >> 6;
  if (lane < MLP_H) { sred[w][lane] = msumv; sred[w][MLP_H+lane] = msqv; }
  __syncthreads();
  int t = threadIdx.x;
  if (t < 2*MLP_H)
    unsafeAtomicAdd(&gstat[t], sred[0][t]+sred[1][t]+sred[2][t]+sred[3][t]);
}

// update stage 2: m = relu(au1*zu1+cu1); tu = relu(m@w2+b2); stats of tu
__global__ __launch_bounds__(TPB) void k_upd2(const float* __restrict__ zu1,
                                              const float* __restrict__ coefu1, // a[32]|c[32]
                                              const float* __restrict__ w2,
                                              const float* __restrict__ b2,
                                              float* __restrict__ tu,
                                              float* __restrict__ gstat) {
  int i = blockIdx.x * TPB + threadIdx.x;
  bool valid = i < N_NODES;
  float m1[MLP_H];
#pragma unroll
  for (int k = 0; k < MLP_H; ++k) m1[k] = 0.f;
  if (valid) {
    const float4* zp = reinterpret_cast<const float4*>(zu1 + (size_t)i * MLP_H);
#pragma unroll
    for (int q = 0; q < MLP_H/4; ++q) {
      float4 z = zp[q];
      int k = 4*q;
      m1[k]   = fmaxf(coefu1[k]  *z.x + coefu1[MLP_H+k],   0.f);
      m1[k+1] = fmaxf(coefu1[k+1]*z.y + coefu1[MLP_H+k+1], 0.f);
      m1[k+2] = fmaxf(coefu1[k+2]*z.z + coefu1[MLP_H+k+2], 0.f);
      m1[k+3] = fmaxf(coefu1[k+3]*z.w + coefu1[MLP_H+k+3], 0.f);
    }
  }
  int lane = threadIdx.x & 63;
  float msumv = 0.f, msqv = 0.f;
#pragma unroll 2
  for (int j4 = 0; j4 < HID/4; ++j4) {
    float tv[4];
#pragma unroll
    for (int c = 0; c < 4; ++c) {
      int j = j4*4 + c;
      float v = 0.f;
      if (valid) {
        v = b2[j];
#pragma unroll
        for (int k = 0; k < MLP_H; ++k) v += m1[k] * w2[k*HID + j];
        v = fmaxf(v, 0.f);
      }
      tv[c] = v;
      float s = wsum(v);
      float q = wsum(v*v);
      if (lane == j) { msumv = s; msqv = q; }
    }
    if (valid) {
      float4 o = {tv[0], tv[1], tv[2], tv[3]};
      *reinterpret_cast<float4*>(tu + (size_t)i * HID + j4*4) = o;
    }
  }
  __shared__ float sred[4][2*HID];
  int w = threadIdx.x >> 6;
  sred[w][lane] = msumv; sred[w][HID+lane] = msqv;
  __syncthreads();
  int t = threadIdx.x;
  if (t < 2*HID)
    unsafeAtomicAdd(&gstat[t], sred[0][t]+sred[1][t]+sred[2][t]+sred[3][t]);
}

// residual: h += au2*tu + cu2
__global__ __launch_bounds__(TPB) void k_resid(float* __restrict__ h,
                                               const float* __restrict__ tu,
                                               const float* __restrict__ coefu2) { // a[64]|c[64]
  int idx = blockIdx.x * TPB + threadIdx.x;   // over N_NODES*16 float4 groups
  if (idx >= N_NODES * (HID/4)) return;
  int j0 = (idx & (HID/4 - 1)) * 4;
  float4 hv = reinterpret_cast<const float4*>(h)[idx];
  float4 tv = reinterpret_cast<const float4*>(tu)[idx];
  float4 a = *reinterpret_cast<const float4*>(coefu2 + j0);
  float4 c = *reinterpret_cast<const float4*>(coefu2 + HID + j0);
  hv.x += a.x*tv.x + c.x;
  hv.y += a.y*tv.y + c.y;
  hv.z += a.z*tv.z + c.z;
  hv.w += a.w*tv.w + c.w;
  reinterpret_cast<float4*>(h)[idx] = hv;
}

// BN coefficient computation: a = g*rsqrt(var+eps), c = be - a*mu
__global__ void k_coef(const float* __restrict__ gstat, int nfeat, float invcnt,
                       const float* __restrict__ g, const float* __restrict__ be,
                       float* __restrict__ coef) {
  int j = threadIdx.x;
  if (j >= nfeat) return;
  float mu = gstat[j] * invcnt;
  float var = fmaxf(gstat[nfeat + j] * invcnt - mu*mu, 0.f);
  float r = rsqrtf(var + EPS);
  float a = g[j] * r;
  coef[j] = a;
  coef[nfeat + j] = be[j] - a * mu;
}

// mean-pool per graph + head: out[g] = relu(mean_nodes(h) @ ow + ob)
__global__ __launch_bounds__(TPB) void k_pool_head(const float* __restrict__ h,
                                                   const int* __restrict__ batch,
                                                   const float* __restrict__ ow,
                                                   const float* __restrict__ ob,
                                                   float* __restrict__ out) {
  int g = blockIdx.x;
  int lo = 0, hi = N_NODES;
  while (lo < hi) { int mid = (lo+hi) >> 1; if (batch[mid] < g) lo = mid+1; else hi = mid; }
  int start = lo;
  lo = start; hi = N_NODES;
  while (lo < hi) { int mid = (lo+hi) >> 1; if (batch[mid] < g+1) lo = mid+1; else hi = mid; }
  int end = lo;
  int j = threadIdx.x & 63;
  int sub = threadIdx.x >> 6;
  float acc = 0.f;
  for (int n = start + sub; n < end; n += 4) acc += h[(size_t)n*HID + j];
  __shared__ float red[TPB];
  red[threadIdx.x] = acc;
  __syncthreads();
  if (threadIdx.x < 64) {
    float s = red[threadIdx.x] + red[64+threadIdx.x] + red[128+threadIdx.x] + red[192+threadIdx.x];
    float cnt = (float)(end - start);
    float pooled = s / fmaxf(cnt, 1.0f);
    float v = pooled * ow[threadIdx.x];
    v = wsum(v);
    if (threadIdx.x == 0) out[g] = fmaxf(v + ob[0], 0.f);
  }
}

// -------------------- launch --------------------
extern "C" void kernel_launch(void* const* d_in, const int* in_sizes, int n_in,
                              void* d_out, int out_size, void* d_ws, size_t ws_size,
                              hipStream_t stream) {
  const float* x       = (const float*)d_in[0];
  const int*   ei      = (const int*)  d_in[1];
  const float* ea      = (const float*)d_in[2];
  const int*   batch   = (const int*)  d_in[3];
  const float* lin_w   = (const float*)d_in[4];
  const float* lin_b   = (const float*)d_in[5];
  const float* msg_w1  = (const float*)d_in[6];
  const float* msg_b1  = (const float*)d_in[7];
  const float* msg_g1  = (const float*)d_in[8];
  const float* msg_be1 = (const float*)d_in[9];
  const float* msg_w2  = (const float*)d_in[10];
  const float* msg_b2  = (const float*)d_in[11];
  const float* msg_g2  = (const float*)d_in[12];
  const float* msg_be2 = (const float*)d_in[13];
  const float* upd_w1  = (const float*)d_in[14];
  const float* upd_b1  = (const float*)d_in[15];
  const float* upd_g1  = (const float*)d_in[16];
  const float* upd_be1 = (const float*)d_in[17];
  const float* upd_w2  = (const float*)d_in[18];
  const float* upd_b2  = (const float*)d_in[19];
  const float* upd_g2  = (const float*)d_in[20];
  const float* upd_be2 = (const float*)d_in[21];
  const float* out_w   = (const float*)d_in[22];
  const float* out_b   = (const float*)d_in[23];
  float* out = (float*)d_out;

  float* W     = (float*)d_ws;
  float* h     = W;                       // 6,400,000
  float* z1    = W + 6400000;             // 25,600,000
  float* agg   = W + 32000000;            // 6,400,000
  float* zu1   = W + 38400000;            // 3,200,000
  float* tu    = W + 41600000;            // 6,400,000
  float* stats = W + 48000000;            // 3*384
  float* coefs = W + 48001152;            // 3*384
  int*   deg   = (int*)(W + 48002304);    // 100,000 ints

  hipMemsetAsync(stats, 0, 3*384*sizeof(float), stream);
  hipMemsetAsync(deg, 0, N_NODES*sizeof(int), stream);

  k_deg<<<N_EDGES/TPB, TPB, 0, stream>>>(ei, deg);
  k_lin_in<<<(N_NODES+TPB-1)/TPB, TPB, 0, stream>>>(x, lin_w, lin_b, h);

  for (int l = 0; l < 3; ++l) {
    const float* mw1 = msg_w1 + (size_t)l*129*MLP_H;
    const float* mb1 = msg_b1 + l*MLP_H;
    const float* mg1 = msg_g1 + l*MLP_H;
    const float* mbe1= msg_be1 + l*MLP_H;
    const float* mw2 = msg_w2 + (size_t)l*MLP_H*HID;
    const float* mb2 = msg_b2 + l*HID;
    const float* mg2 = msg_g2 + l*HID;
    const float* mbe2= msg_be2 + l*HID;
    const float* uw1 = upd_w1 + (size_t)l*128*MLP_H;
    const float* ub1 = upd_b1 + l*MLP_H;
    const float* ug1 = upd_g1 + l*MLP_H;
    const float* ube1= upd_be1 + l*MLP_H;
    const float* uw2 = upd_w2 + (size_t)l*MLP_H*HID;
    const float* ub2 = upd_b2 + l*HID;
    const float* ug2 = upd_g2 + l*HID;
    const float* ube2= upd_be2 + l*HID;
    float* st = stats + l*384;
    float* cf = coefs + l*384;

    hipMemsetAsync(agg, 0, (size_t)N_NODES*HID*sizeof(float), stream);
    k_msg1<<<N_EDGES/TPB, TPB, 0, stream>>>(h, ei, ea, mw1, mb1, z1, st);
    k_coef<<<1, 64, 0, stream>>>(st, MLP_H, 1.f/N_EDGES, mg1, mbe1, cf);
    k_msg2_scatter<<<N_EDGES/TPB, TPB, 0, stream>>>(z1, ei, cf, mw2, mb2, agg, st+64);
    k_coef<<<1, 64, 0, stream>>>(st+64, HID, 1.f/N_EDGES, mg2, mbe2, cf+64);
    k_upd1<<<(N_NODES+TPB-1)/TPB, TPB, 0, stream>>>(h, agg, deg, cf+64, uw1, ub1, zu1, st+192);
    k_coef<<<1, 64, 0, stream>>>(st+192, MLP_H, 1.f/N_NODES, ug1, ube1, cf+192);
    k_upd2<<<(N_NODES+TPB-1)/TPB, TPB, 0, stream>>>(zu1, cf+192, uw2, ub2, tu, st+256);
    k_coef<<<1, 64, 0, stream>>>(st+256, HID, 1.f/N_NODES, ug2, ube2, cf+256);
    k_resid<<<(N_NODES*(HID/4)+TPB-1)/TPB, TPB, 0, stream>>>(h, tu, cf+256);
  }

  k_pool_head<<<NUM_GRAPHS, TPB, 0, stream>>>(h, batch, out_w, out_b, out);
}

// Round 2
// 4451.597 us; speedup vs baseline: 1.9882x; 1.9882x over previous
//
#include <hip/hip_runtime.h>
#include <hip/hip_bf16.h>

#define N_NODES   100000
#define N_EDGES   800000
#define NUM_GRAPHS 512
#define IN_DIM    16
#define HID       64
#define MLP_H     32
#define EPS       1e-5f
#define TPB       256
#define SCAN_B    1024
#define NCHUNK    ((N_NODES + SCAN_B - 1) / SCAN_B)   // 98

__device__ __forceinline__ float bcast_lane(float v, int kk) {
  return __int_as_float(__builtin_amdgcn_readlane(__float_as_int(v), kk));
}

// -------------------- CSR build --------------------
__global__ __launch_bounds__(TPB) void k_deg(const int* __restrict__ ei, int* __restrict__ deg) {
  int e = blockIdx.x * TPB + threadIdx.x;
  if (e < N_EDGES) atomicAdd(&deg[ei[N_EDGES + e]], 1);
}

__global__ __launch_bounds__(SCAN_B) void k_scan_part(const int* __restrict__ deg,
                                                      int* __restrict__ partials) {
  __shared__ int red[SCAN_B];
  int i = blockIdx.x * SCAN_B + threadIdx.x;
  red[threadIdx.x] = (i < N_NODES) ? deg[i] : 0;
  __syncthreads();
  for (int off = SCAN_B / 2; off > 0; off >>= 1) {
    if (threadIdx.x < off) red[threadIdx.x] += red[threadIdx.x + off];
    __syncthreads();
  }
  if (threadIdx.x == 0) partials[blockIdx.x] = red[0];
}

__global__ void k_scan_mid(int* __restrict__ partials, int* __restrict__ row_start) {
  int run = 0;
  for (int b = 0; b < NCHUNK; ++b) { int t = partials[b]; partials[b] = run; run += t; }
  row_start[N_NODES] = run;  // == N_EDGES
}

__global__ __launch_bounds__(SCAN_B) void k_scan_fin(const int* __restrict__ deg,
                                                     const int* __restrict__ partials,
                                                     int* __restrict__ row_start,
                                                     int* __restrict__ cursor) {
  __shared__ int buf[2][SCAN_B];
  int t = threadIdx.x, i = blockIdx.x * SCAN_B + t;
  int v = (i < N_NODES) ? deg[i] : 0;
  buf[0][t] = v;
  __syncthreads();
  int cur = 0;
  for (int off = 1; off < SCAN_B; off <<= 1) {
    int nv = buf[cur][t] + ((t >= off) ? buf[cur][t - off] : 0);
    buf[cur ^ 1][t] = nv; cur ^= 1;
    __syncthreads();
  }
  if (i < N_NODES) {
    int excl = buf[cur][t] - v + partials[blockIdx.x];
    row_start[i] = excl;
    cursor[i] = excl;
  }
}

__global__ __launch_bounds__(TPB) void k_fill(const int* __restrict__ ei,
                                              const float* __restrict__ ea,
                                              int* __restrict__ cursor,
                                              int* __restrict__ srcS,
                                              float* __restrict__ eaS) {
  int e = blockIdx.x * TPB + threadIdx.x;
  if (e >= N_EDGES) return;
  int dst = ei[N_EDGES + e];
  int pos = atomicAdd(&cursor[dst], 1);
  srcS[pos] = ei[e];
  eaS[pos] = ea[e];
}

// -------------------- input projection --------------------
__global__ __launch_bounds__(TPB) void k_lin_in(const float* __restrict__ x,
                                                const float* __restrict__ w,
                                                const float* __restrict__ b,
                                                float* __restrict__ h) {
  int i = blockIdx.x * TPB + threadIdx.x;
  if (i >= N_NODES) return;
  float xi[IN_DIM];
  const float4* xp = reinterpret_cast<const float4*>(x + (size_t)i * IN_DIM);
#pragma unroll
  for (int q = 0; q < 4; ++q) {
    float4 v = xp[q];
    xi[4*q] = v.x; xi[4*q+1] = v.y; xi[4*q+2] = v.z; xi[4*q+3] = v.w;
  }
  float4* hp = reinterpret_cast<float4*>(h + (size_t)i * HID);
#pragma unroll
  for (int j4 = 0; j4 < HID/4; ++j4) {
    float o[4];
#pragma unroll
    for (int c = 0; c < 4; ++c) {
      int j = j4*4 + c;
      float acc = b[j];
#pragma unroll
      for (int k = 0; k < IN_DIM; ++k) acc += xi[k] * w[k*HID + j];
      o[c] = acc;
    }
    float4 ov = {o[0], o[1], o[2], o[3]};
    hp[j4] = ov;
  }
}

// -------------------- per-node msg projections: P = h@W1[0:64]+b1, Q = h@W1[64:128] ----
__global__ __launch_bounds__(TPB) void k_pq(const float* __restrict__ h,
                                            const float* __restrict__ w1,
                                            const float* __restrict__ b1,
                                            float* __restrict__ P,
                                            float* __restrict__ Q) {
  int i = blockIdx.x * TPB + threadIdx.x;
  if (i >= N_NODES) return;
  float p[MLP_H], q[MLP_H];
#pragma unroll
  for (int j = 0; j < MLP_H; ++j) { p[j] = b1[j]; q[j] = 0.f; }
  const float4* hp = reinterpret_cast<const float4*>(h + (size_t)i * HID);
#pragma unroll 2
  for (int k4 = 0; k4 < 16; ++k4) {
    float4 a = hp[k4];
    const float* wp = w1 + (k4*4) * MLP_H;
    const float* wq = w1 + (64 + k4*4) * MLP_H;
#pragma unroll
    for (int j = 0; j < MLP_H; ++j) {
      p[j] += a.x*wp[j] + a.y*wp[MLP_H+j] + a.z*wp[2*MLP_H+j] + a.w*wp[3*MLP_H+j];
      q[j] += a.x*wq[j] + a.y*wq[MLP_H+j] + a.z*wq[2*MLP_H+j] + a.w*wq[3*MLP_H+j];
    }
  }
  float4* pp = reinterpret_cast<float4*>(P + (size_t)i * MLP_H);
  float4* qp = reinterpret_cast<float4*>(Q + (size_t)i * MLP_H);
#pragma unroll
  for (int c = 0; c < MLP_H/4; ++c) {
    float4 pv = {p[4*c], p[4*c+1], p[4*c+2], p[4*c+3]};
    float4 qv = {q[4*c], q[4*c+1], q[4*c+2], q[4*c+3]};
    pp[c] = pv; qp[c] = qv;
  }
}

// -------------------- z1 stats (pre-BN1), one wave per node, 2 edges/iter --------------
__global__ __launch_bounds__(TPB, 6) void k_zstats(const float* __restrict__ P,
                                                   const float* __restrict__ Q,
                                                   const int* __restrict__ srcS,
                                                   const float* __restrict__ eaS,
                                                   const int* __restrict__ row_start,
                                                   const float* __restrict__ w1,
                                                   float* __restrict__ gstat) {
  int wid = blockIdx.x * 4 + (threadIdx.x >> 6);
  int lane = threadIdx.x & 63, k = lane & 31;
  float s = 0.f, q = 0.f;
  if (wid < N_NODES) {
    int start = row_start[wid], end = row_start[wid + 1];
    float Pk = P[(size_t)wid * MLP_H + k];
    float weak = w1[128 * MLP_H + k];
    for (int e = start + (lane >> 5); e < end; e += 2) {
      int src = srcS[e];
      float z = Pk + Q[(size_t)src * MLP_H + k] + eaS[e] * weak;
      s += z; q = fmaf(z, z, q);
    }
  }
  s += __shfl_xor(s, 32, 64);
  q += __shfl_xor(q, 32, 64);
  __shared__ float ls[4][MLP_H], lq[4][MLP_H];
  int w = threadIdx.x >> 6;
  if (lane < MLP_H) { ls[w][lane] = s; lq[w][lane] = q; }
  __syncthreads();
  int t = threadIdx.x;
  if (t < MLP_H) {
    unsafeAtomicAdd(&gstat[t], ls[0][t] + ls[1][t] + ls[2][t] + ls[3][t]);
    unsafeAtomicAdd(&gstat[MLP_H + t], lq[0][t] + lq[1][t] + lq[2][t] + lq[3][t]);
  }
}

// -------------------- fused msg2 + aggregate + t-stats, one wave per node -------------
// m1[k] = relu(a1*(P[dst]+Q[src]+ea*wea)+c1) in lane k; t[j] = relu(b2 + sum_k m1*w2);
// agg[dst][j] accumulated in registers (lane j), coalesced write; no atomics.
__global__ __launch_bounds__(TPB, 6) void k_msg(const float* __restrict__ P,
                                                const float* __restrict__ Q,
                                                const int* __restrict__ srcS,
                                                const float* __restrict__ eaS,
                                                const int* __restrict__ row_start,
                                                const float* __restrict__ w1,
                                                const float* __restrict__ coef1,
                                                const float* __restrict__ w2,
                                                const float* __restrict__ b2,
                                                float* __restrict__ agg,
                                                float* __restrict__ gstat) {
  int wid = blockIdx.x * 4 + (threadIdx.x >> 6);
  int lane = threadIdx.x & 63, k = lane & 31;
  float w2col[MLP_H];
#pragma unroll
  for (int kk = 0; kk < MLP_H; ++kk) w2col[kk] = w2[kk * HID + lane];
  float b2j = b2[lane];
  float aggj = 0.f, sj = 0.f, qj = 0.f;
  if (wid < N_NODES) {
    int start = row_start[wid], end = row_start[wid + 1];
    float Pk = P[(size_t)wid * MLP_H + k];
    float weak = w1[128 * MLP_H + k];
    float a1k = coef1[k], c1k = coef1[MLP_H + k];
    for (int e = start; e < end; ++e) {
      int src = srcS[e];
      float eav = eaS[e];
      float z = Pk + Q[(size_t)src * MLP_H + k] + eav * weak;
      float m = fmaxf(fmaf(a1k, z, c1k), 0.f);
      float v0 = b2j, v1 = 0.f;
#pragma unroll
      for (int kk = 0; kk < MLP_H; kk += 2) {
        v0 = fmaf(bcast_lane(m, kk),     w2col[kk],     v0);
        v1 = fmaf(bcast_lane(m, kk + 1), w2col[kk + 1], v1);
      }
      float v = fmaxf(v0 + v1, 0.f);
      aggj += v; sj += v; qj = fmaf(v, v, qj);
    }
    agg[(size_t)wid * HID + lane] = aggj;
  }
  __shared__ float ls[4][HID], lq[4][HID];
  int w = threadIdx.x >> 6;
  ls[w][lane] = sj; lq[w][lane] = qj;
  __syncthreads();
  int t = threadIdx.x;
  if (t < HID) {
    unsafeAtomicAdd(&gstat[t], ls[0][t] + ls[1][t] + ls[2][t] + ls[3][t]);
    unsafeAtomicAdd(&gstat[HID + t], lq[0][t] + lq[1][t] + lq[2][t] + lq[3][t]);
  }
}

// -------------------- update stage 1 (no stats) --------------------
__global__ __launch_bounds__(TPB) void k_upd1(const float* __restrict__ h,
                                              const float* __restrict__ agg,
                                              const int* __restrict__ deg,
                                              const float* __restrict__ coef2, // a[64]|c[64]
                                              const float* __restrict__ w1,
                                              const float* __restrict__ b1,
                                              float* __restrict__ zu1) {
  int i = blockIdx.x * TPB + threadIdx.x;
  if (i >= N_NODES) return;
  float acc[MLP_H];
#pragma unroll
  for (int j = 0; j < MLP_H; ++j) acc[j] = b1[j];
  const float4* hp = reinterpret_cast<const float4*>(h + (size_t)i * HID);
#pragma unroll 2
  for (int k4 = 0; k4 < 16; ++k4) {
    float4 a = hp[k4];
    const float* wr = w1 + (k4*4) * MLP_H;
#pragma unroll
    for (int j = 0; j < MLP_H; ++j)
      acc[j] += a.x*wr[j] + a.y*wr[MLP_H+j] + a.z*wr[2*MLP_H+j] + a.w*wr[3*MLP_H+j];
  }
  float degf = (float)deg[i];
  const float4* ap = reinterpret_cast<const float4*>(agg + (size_t)i * HID);
#pragma unroll 2
  for (int k4 = 0; k4 < 16; ++k4) {
    float4 g4 = ap[k4];
    int k = k4*4;
    float a0 = coef2[k]  *g4.x + coef2[HID+k]  *degf;
    float a1 = coef2[k+1]*g4.y + coef2[HID+k+1]*degf;
    float a2 = coef2[k+2]*g4.z + coef2[HID+k+2]*degf;
    float a3 = coef2[k+3]*g4.w + coef2[HID+k+3]*degf;
    const float* wr = w1 + (64 + k) * MLP_H;
#pragma unroll
    for (int j = 0; j < MLP_H; ++j)
      acc[j] += a0*wr[j] + a1*wr[MLP_H+j] + a2*wr[2*MLP_H+j] + a3*wr[3*MLP_H+j];
  }
  float4* zp = reinterpret_cast<float4*>(zu1 + (size_t)i * MLP_H);
#pragma unroll
  for (int c = 0; c < MLP_H/4; ++c) {
    float4 o = {acc[4*c], acc[4*c+1], acc[4*c+2], acc[4*c+3]};
    zp[c] = o;
  }
}

// -------------------- update stage 2 (no stats) --------------------
__global__ __launch_bounds__(TPB) void k_upd2(const float* __restrict__ zu1,
                                              const float* __restrict__ cf,   // a[32]|c[32]
                                              const float* __restrict__ w2,
                                              const float* __restrict__ b2,
                                              float* __restrict__ tu) {
  int i = blockIdx.x * TPB + threadIdx.x;
  if (i >= N_NODES) return;
  float m1[MLP_H];
  const float4* zp = reinterpret_cast<const float4*>(zu1 + (size_t)i * MLP_H);
#pragma unroll
  for (int c = 0; c < MLP_H/4; ++c) {
    float4 z = zp[c];
    int k = 4*c;
    m1[k]   = fmaxf(cf[k]  *z.x + cf[MLP_H+k],   0.f);
    m1[k+1] = fmaxf(cf[k+1]*z.y + cf[MLP_H+k+1], 0.f);
    m1[k+2] = fmaxf(cf[k+2]*z.z + cf[MLP_H+k+2], 0.f);
    m1[k+3] = fmaxf(cf[k+3]*z.w + cf[MLP_H+k+3], 0.f);
  }
#pragma unroll 2
  for (int j4 = 0; j4 < HID/4; ++j4) {
    float tv[4];
#pragma unroll
    for (int c = 0; c < 4; ++c) {
      int j = j4*4 + c;
      float v = b2[j];
#pragma unroll
      for (int k = 0; k < MLP_H; ++k) v += m1[k] * w2[k*HID + j];
      tv[c] = fmaxf(v, 0.f);
    }
    float4 o = {tv[0], tv[1], tv[2], tv[3]};
    *reinterpret_cast<float4*>(tu + (size_t)i * HID + j4*4) = o;
  }
}

// -------------------- column stats (sum, sumsq), feature-per-lane --------------------
template <int NF>
__global__ __launch_bounds__(TPB) void k_colstats(const float* __restrict__ X,
                                                  int nrows, float* __restrict__ gstat) {
  const int RPB = TPB / NF;
  int f = threadIdx.x % NF;
  int rloc = threadIdx.x / NF;
  float s = 0.f, q = 0.f;
  for (int r = blockIdx.x * RPB + rloc; r < nrows; r += gridDim.x * RPB) {
    float v = X[(size_t)r * NF + f];
    s += v; q = fmaf(v, v, q);
  }
  __shared__ float ls[TPB], lq[TPB];
  ls[threadIdx.x] = s; lq[threadIdx.x] = q;
  __syncthreads();
  if (threadIdx.x < NF) {
    float ss = 0.f, qq = 0.f;
#pragma unroll
    for (int r = 0; r < RPB; ++r) { ss += ls[r*NF + f]; qq += lq[r*NF + f]; }
    unsafeAtomicAdd(&gstat[f], ss);
    unsafeAtomicAdd(&gstat[NF + f], qq);
  }
}

// -------------------- residual --------------------
__global__ __launch_bounds__(TPB) void k_resid(float* __restrict__ h,
                                               const float* __restrict__ tu,
                                               const float* __restrict__ cf) { // a[64]|c[64]
  int idx = blockIdx.x * TPB + threadIdx.x;
  if (idx >= N_NODES * (HID/4)) return;
  int j0 = (idx & (HID/4 - 1)) * 4;
  float4 hv = reinterpret_cast<const float4*>(h)[idx];
  float4 tv = reinterpret_cast<const float4*>(tu)[idx];
  float4 a = *reinterpret_cast<const float4*>(cf + j0);
  float4 c = *reinterpret_cast<const float4*>(cf + HID + j0);
  hv.x += a.x*tv.x + c.x;
  hv.y += a.y*tv.y + c.y;
  hv.z += a.z*tv.z + c.z;
  hv.w += a.w*tv.w + c.w;
  reinterpret_cast<float4*>(h)[idx] = hv;
}

// -------------------- BN coefficients --------------------
__global__ void k_coef(const float* __restrict__ gstat, int nfeat, float invcnt,
                       const float* __restrict__ g, const float* __restrict__ be,
                       float* __restrict__ coef) {
  int j = threadIdx.x;
  if (j >= nfeat) return;
  float mu = gstat[j] * invcnt;
  float var = fmaxf(gstat[nfeat + j] * invcnt - mu*mu, 0.f);
  float r = rsqrtf(var + EPS);
  float a = g[j] * r;
  coef[j] = a;
  coef[nfeat + j] = be[j] - a * mu;
}

// -------------------- pool + head --------------------
__global__ __launch_bounds__(TPB) void k_pool_head(const float* __restrict__ h,
                                                   const int* __restrict__ batch,
                                                   const float* __restrict__ ow,
                                                   const float* __restrict__ ob,
                                                   float* __restrict__ out) {
  int g = blockIdx.x;
  int lo = 0, hi = N_NODES;
  while (lo < hi) { int mid = (lo+hi) >> 1; if (batch[mid] < g) lo = mid+1; else hi = mid; }
  int start = lo;
  lo = start; hi = N_NODES;
  while (lo < hi) { int mid = (lo+hi) >> 1; if (batch[mid] < g+1) lo = mid+1; else hi = mid; }
  int end = lo;
  int j = threadIdx.x & 63;
  int sub = threadIdx.x >> 6;
  float acc = 0.f;
  for (int n = start + sub; n < end; n += 4) acc += h[(size_t)n*HID + j];
  __shared__ float red[TPB];
  red[threadIdx.x] = acc;
  __syncthreads();
  if (threadIdx.x < 64) {
    float s = red[threadIdx.x] + red[64+threadIdx.x] + red[128+threadIdx.x] + red[192+threadIdx.x];
    float cnt = (float)(end - start);
    float pooled = s / fmaxf(cnt, 1.0f);
    float v = pooled * ow[threadIdx.x];
    v += __shfl_xor(v, 1, 64);  v += __shfl_xor(v, 2, 64);
    v += __shfl_xor(v, 4, 64);  v += __shfl_xor(v, 8, 64);
    v += __shfl_xor(v, 16, 64); v += __shfl_xor(v, 32, 64);
    if (threadIdx.x == 0) out[g] = fmaxf(v + ob[0], 0.f);
  }
}

// -------------------- launch --------------------
extern "C" void kernel_launch(void* const* d_in, const int* in_sizes, int n_in,
                              void* d_out, int out_size, void* d_ws, size_t ws_size,
                              hipStream_t stream) {
  const float* x       = (const float*)d_in[0];
  const int*   ei      = (const int*)  d_in[1];
  const float* ea      = (const float*)d_in[2];
  const int*   batch   = (const int*)  d_in[3];
  const float* lin_w   = (const float*)d_in[4];
  const float* lin_b   = (const float*)d_in[5];
  const float* msg_w1  = (const float*)d_in[6];
  const float* msg_b1  = (const float*)d_in[7];
  const float* msg_g1  = (const float*)d_in[8];
  const float* msg_be1 = (const float*)d_in[9];
  const float* msg_w2  = (const float*)d_in[10];
  const float* msg_b2  = (const float*)d_in[11];
  const float* msg_g2  = (const float*)d_in[12];
  const float* msg_be2 = (const float*)d_in[13];
  const float* upd_w1  = (const float*)d_in[14];
  const float* upd_b1  = (const float*)d_in[15];
  const float* upd_g1  = (const float*)d_in[16];
  const float* upd_be1 = (const float*)d_in[17];
  const float* upd_w2  = (const float*)d_in[18];
  const float* upd_b2  = (const float*)d_in[19];
  const float* upd_g2  = (const float*)d_in[20];
  const float* upd_be2 = (const float*)d_in[21];
  const float* out_w   = (const float*)d_in[22];
  const float* out_b   = (const float*)d_in[23];
  float* out = (float*)d_out;

  float* W     = (float*)d_ws;
  float* h     = W;                       // 6,400,000
  float* P     = W + 6400000;             // 3,200,000
  float* Qb    = W + 9600000;             // 3,200,000
  float* agg   = W + 12800000;            // 6,400,000
  float* zu1   = W + 19200000;            // 3,200,000
  float* tu    = W + 22400000;            // 6,400,000
  float* eaS   = W + 28800000;            // 800,000
  float* stats = W + 29600000;            // 3*384
  float* coefs = W + 29601152;            // 3*384
  int*   ib    = (int*)(W + 29602304);
  int* deg       = ib;                    // 100,000
  int* row_start = ib + 100000;           // 100,001
  int* cursor    = ib + 200002;           // 100,000
  int* srcS      = ib + 300002;           // 800,000
  int* partials  = ib + 1100002;          // NCHUNK

  hipMemsetAsync(stats, 0, 3*384*sizeof(float), stream);
  hipMemsetAsync(deg, 0, N_NODES*sizeof(int), stream);

  // CSR build (same every call; rebuilt deterministically)
  k_deg<<<N_EDGES/TPB, TPB, 0, stream>>>(ei, deg);
  k_scan_part<<<NCHUNK, SCAN_B, 0, stream>>>(deg, partials);
  k_scan_mid<<<1, 1, 0, stream>>>(partials, row_start);
  k_scan_fin<<<NCHUNK, SCAN_B, 0, stream>>>(deg, partials, row_start, cursor);
  k_fill<<<N_EDGES/TPB, TPB, 0, stream>>>(ei, ea, cursor, srcS, eaS);

  k_lin_in<<<(N_NODES+TPB-1)/TPB, TPB, 0, stream>>>(x, lin_w, lin_b, h);

  const int NODE_BLKS = (N_NODES + TPB - 1) / TPB;       // 391
  const int WAVE_BLKS = (N_NODES + 3) / 4;               // 25000 (4 waves/block)

  for (int l = 0; l < 3; ++l) {
    const float* mw1 = msg_w1 + (size_t)l*129*MLP_H;
    const float* mb1 = msg_b1 + l*MLP_H;
    const float* mg1 = msg_g1 + l*MLP_H;
    const float* mbe1= msg_be1 + l*MLP_H;
    const float* mw2 = msg_w2 + (size_t)l*MLP_H*HID;
    const float* mb2 = msg_b2 + l*HID;
    const float* mg2 = msg_g2 + l*HID;
    const float* mbe2= msg_be2 + l*HID;
    const float* uw1 = upd_w1 + (size_t)l*128*MLP_H;
    const float* ub1 = upd_b1 + l*MLP_H;
    const float* ug1 = upd_g1 + l*MLP_H;
    const float* ube1= upd_be1 + l*MLP_H;
    const float* uw2 = upd_w2 + (size_t)l*MLP_H*HID;
    const float* ub2 = upd_b2 + l*HID;
    const float* ug2 = upd_g2 + l*HID;
    const float* ube2= upd_be2 + l*HID;
    float* st = stats + l*384;
    float* cf = coefs + l*384;

    k_pq<<<NODE_BLKS, TPB, 0, stream>>>(h, mw1, mb1, P, Qb);
    k_zstats<<<WAVE_BLKS, TPB, 0, stream>>>(P, Qb, srcS, eaS, row_start, mw1, st);
    k_coef<<<1, 64, 0, stream>>>(st, MLP_H, 1.f/N_EDGES, mg1, mbe1, cf);
    k_msg<<<WAVE_BLKS, TPB, 0, stream>>>(P, Qb, srcS, eaS, row_start, mw1, cf, mw2, mb2,
                                         agg, st+64);
    k_coef<<<1, 64, 0, stream>>>(st+64, HID, 1.f/N_EDGES, mg2, mbe2, cf+64);
    k_upd1<<<NODE_BLKS, TPB, 0, stream>>>(h, agg, deg, cf+64, uw1, ub1, zu1);
    k_colstats<MLP_H><<<512, TPB, 0, stream>>>(zu1, N_NODES, st+192);
    k_coef<<<1, 64, 0, stream>>>(st+192, MLP_H, 1.f/N_NODES, ug1, ube1, cf+192);
    k_upd2<<<NODE_BLKS, TPB, 0, stream>>>(zu1, cf+192, uw2, ub2, tu);
    k_colstats<HID><<<512, TPB, 0, stream>>>(tu, N_NODES, st+256);
    k_coef<<<1, 64, 0, stream>>>(st+256, HID, 1.f/N_NODES, ug2, ube2, cf+256);
    k_resid<<<(N_NODES*(HID/4)+TPB-1)/TPB, TPB, 0, stream>>>(h, tu, cf+256);
  }

  k_pool_head<<<NUM_GRAPHS, TPB, 0, stream>>>(h, batch, out_w, out_b, out);
}

// Round 3
// 1470.724 us; speedup vs baseline: 6.0178x; 3.0268x over previous
//
#include <hip/hip_runtime.h>
#include <hip/hip_bf16.h>

#define N_NODES   100000
#define N_EDGES   800000
#define NUM_GRAPHS 512
#define IN_DIM    16
#define HID       64
#define MLP_H     32
#define EPS       1e-5f
#define TPB       256
#define SCAN_B    1024
#define NCHUNK    ((N_NODES + SCAN_B - 1) / SCAN_B)   // 98
#define GSB       2048                                // grid-stride blocks for edge kernels

__device__ __forceinline__ float bcast_lane(float v, int kk) {
  return __int_as_float(__builtin_amdgcn_readlane(__float_as_int(v), kk));
}
__device__ __forceinline__ float shfl_bcast(float v, int srcl) {
  return __shfl(v, srcl, 64);
}
__device__ __forceinline__ float wsum(float v) {
  v += __shfl_xor(v, 1, 64);
  v += __shfl_xor(v, 2, 64);
  v += __shfl_xor(v, 4, 64);
  v += __shfl_xor(v, 8, 64);
  v += __shfl_xor(v, 16, 64);
  v += __shfl_xor(v, 32, 64);
  return v;
}

// -------------------- CSR build --------------------
__global__ __launch_bounds__(TPB) void k_deg(const int* __restrict__ ei, int* __restrict__ deg) {
  int e = blockIdx.x * TPB + threadIdx.x;
  if (e < N_EDGES) atomicAdd(&deg[ei[N_EDGES + e]], 1);
}

__global__ __launch_bounds__(SCAN_B) void k_scan_part(const int* __restrict__ deg,
                                                      int* __restrict__ partials) {
  __shared__ int red[SCAN_B];
  int i = blockIdx.x * SCAN_B + threadIdx.x;
  red[threadIdx.x] = (i < N_NODES) ? deg[i] : 0;
  __syncthreads();
  for (int off = SCAN_B / 2; off > 0; off >>= 1) {
    if (threadIdx.x < off) red[threadIdx.x] += red[threadIdx.x + off];
    __syncthreads();
  }
  if (threadIdx.x == 0) partials[blockIdx.x] = red[0];
}

__global__ void k_scan_mid(int* __restrict__ partials, int* __restrict__ row_start) {
  int run = 0;
  for (int b = 0; b < NCHUNK; ++b) { int t = partials[b]; partials[b] = run; run += t; }
  row_start[N_NODES] = run;  // == N_EDGES
}

__global__ __launch_bounds__(SCAN_B) void k_scan_fin(const int* __restrict__ deg,
                                                     const int* __restrict__ partials,
                                                     int* __restrict__ row_start,
                                                     int* __restrict__ cursor) {
  __shared__ int buf[2][SCAN_B];
  int t = threadIdx.x, i = blockIdx.x * SCAN_B + t;
  int v = (i < N_NODES) ? deg[i] : 0;
  buf[0][t] = v;
  __syncthreads();
  int cur = 0;
  for (int off = 1; off < SCAN_B; off <<= 1) {
    int nv = buf[cur][t] + ((t >= off) ? buf[cur][t - off] : 0);
    buf[cur ^ 1][t] = nv; cur ^= 1;
    __syncthreads();
  }
  if (i < N_NODES) {
    int excl = buf[cur][t] - v + partials[blockIdx.x];
    row_start[i] = excl;
    cursor[i] = excl;
  }
}

__global__ __launch_bounds__(TPB) void k_fill(const int* __restrict__ ei,
                                              const float* __restrict__ ea,
                                              int* __restrict__ cursor,
                                              int* __restrict__ srcS,
                                              float* __restrict__ eaS) {
  int e = blockIdx.x * TPB + threadIdx.x;
  if (e >= N_EDGES) return;
  int dst = ei[N_EDGES + e];
  int pos = atomicAdd(&cursor[dst], 1);
  srcS[pos] = ei[e];
  eaS[pos] = ea[e];
}

// -------------------- input projection --------------------
__global__ __launch_bounds__(TPB) void k_lin_in(const float* __restrict__ x,
                                                const float* __restrict__ w,
                                                const float* __restrict__ b,
                                                float* __restrict__ h) {
  int i = blockIdx.x * TPB + threadIdx.x;
  if (i >= N_NODES) return;
  float xi[IN_DIM];
  const float4* xp = reinterpret_cast<const float4*>(x + (size_t)i * IN_DIM);
#pragma unroll
  for (int q = 0; q < 4; ++q) {
    float4 v = xp[q];
    xi[4*q] = v.x; xi[4*q+1] = v.y; xi[4*q+2] = v.z; xi[4*q+3] = v.w;
  }
  float4* hp = reinterpret_cast<float4*>(h + (size_t)i * HID);
#pragma unroll
  for (int j4 = 0; j4 < HID/4; ++j4) {
    float o[4];
#pragma unroll
    for (int c = 0; c < 4; ++c) {
      int j = j4*4 + c;
      float acc = b[j];
#pragma unroll
      for (int k = 0; k < IN_DIM; ++k) acc += xi[k] * w[k*HID + j];
      o[c] = acc;
    }
    float4 ov = {o[0], o[1], o[2], o[3]};
    hp[j4] = ov;
  }
}

// -------------------- per-node msg projections: P = h@W1[0:64]+b1, Q = h@W1[64:128] ----
__global__ __launch_bounds__(TPB) void k_pq(const float* __restrict__ h,
                                            const float* __restrict__ w1,
                                            const float* __restrict__ b1,
                                            float* __restrict__ P,
                                            float* __restrict__ Q) {
  int i = blockIdx.x * TPB + threadIdx.x;
  if (i >= N_NODES) return;
  float p[MLP_H], q[MLP_H];
#pragma unroll
  for (int j = 0; j < MLP_H; ++j) { p[j] = b1[j]; q[j] = 0.f; }
  const float4* hp = reinterpret_cast<const float4*>(h + (size_t)i * HID);
#pragma unroll 2
  for (int k4 = 0; k4 < 16; ++k4) {
    float4 a = hp[k4];
    const float* wp = w1 + (k4*4) * MLP_H;
    const float* wq = w1 + (64 + k4*4) * MLP_H;
#pragma unroll
    for (int j = 0; j < MLP_H; ++j) {
      p[j] += a.x*wp[j] + a.y*wp[MLP_H+j] + a.z*wp[2*MLP_H+j] + a.w*wp[3*MLP_H+j];
      q[j] += a.x*wq[j] + a.y*wq[MLP_H+j] + a.z*wq[2*MLP_H+j] + a.w*wq[3*MLP_H+j];
    }
  }
  float4* pp = reinterpret_cast<float4*>(P + (size_t)i * MLP_H);
  float4* qp = reinterpret_cast<float4*>(Q + (size_t)i * MLP_H);
#pragma unroll
  for (int c = 0; c < MLP_H/4; ++c) {
    float4 pv = {p[4*c], p[4*c+1], p[4*c+2], p[4*c+3]};
    float4 qv = {q[4*c], q[4*c+1], q[4*c+2], q[4*c+3]};
    pp[c] = pv; qp[c] = qv;
  }
}

// -------------------- z1 stats (pre-BN1): grid-stride, half-wave edge split, pipelined
__global__ __launch_bounds__(TPB, 8) void k_zstats(const float* __restrict__ P,
                                                   const float* __restrict__ Q,
                                                   const int* __restrict__ srcS,
                                                   const float* __restrict__ eaS,
                                                   const int* __restrict__ row_start,
                                                   const float* __restrict__ w1,
                                                   float* __restrict__ gstat) {
  const int lane = threadIdx.x & 63;
  const int k = lane & 31;
  const int half = lane >> 5;
  const float weak = w1[128 * MLP_H + k];
  float s = 0.f, q = 0.f;
  const int wslot = blockIdx.x * 4 + (threadIdx.x >> 6);
  for (int wid = wslot; wid < N_NODES; wid += GSB * 4) {
    const int start = row_start[wid], end = row_start[wid + 1];
    if (end > start) {
      const float Pk = P[(size_t)wid * MLP_H + k];
      const int rounds = (end - start + 1) >> 1;
      int cl = min(start + half, end - 1);
      int srcc = srcS[cl];
      float eac = eaS[cl];
      float qv = Q[(size_t)srcc * MLP_H + k];
      for (int r = 0; r < rounds; ++r) {
        const bool valid = (start + 2*r + half) < end;   // per-lane (half)
        float z = Pk + qv + eac * weak;
        if (r + 1 < rounds) {
          int cn = min(start + 2*(r+1) + half, end - 1);
          int sn = srcS[cn];
          eac = eaS[cn];
          qv = Q[(size_t)sn * MLP_H + k];
        }
        if (valid) { s += z; q = fmaf(z, z, q); }
      }
    }
  }
  s += __shfl_xor(s, 32, 64);
  q += __shfl_xor(q, 32, 64);
  __shared__ float ls[4][MLP_H], lq[4][MLP_H];
  const int w = threadIdx.x >> 6;
  if (lane < MLP_H) { ls[w][lane] = s; lq[w][lane] = q; }
  __syncthreads();
  const int t = threadIdx.x;
  if (t < MLP_H)
    unsafeAtomicAdd(&gstat[t], ls[0][t] + ls[1][t] + ls[2][t] + ls[3][t]);
  else if (t < 2*MLP_H)
    unsafeAtomicAdd(&gstat[t], lq[0][t-MLP_H] + lq[1][t-MLP_H] + lq[2][t-MLP_H] + lq[3][t-MLP_H]);
}

// -------------------- fused msg2 + aggregate + t-stats --------------------
// Half-wave split: lanes 0-31 hold m1 of edge e, lanes 32-63 of edge e+1.
// Every lane j (0..63) accumulates t_e[j] (readlane 0..31, VALU) and t_{e+1}[j]
// (shfl 32..63, LDS pipe). Next round's Q gather issued before the dot chains.
__global__ __launch_bounds__(TPB) void k_msg(const float* __restrict__ P,
                                             const float* __restrict__ Q,
                                             const int* __restrict__ srcS,
                                             const float* __restrict__ eaS,
                                             const int* __restrict__ row_start,
                                             const float* __restrict__ w1,
                                             const float* __restrict__ coef1,
                                             const float* __restrict__ w2,
                                             const float* __restrict__ b2,
                                             float* __restrict__ agg,
                                             float* __restrict__ gstat) {
  const int lane = threadIdx.x & 63;
  const int k = lane & 31;
  const int half = lane >> 5;
  float w2c[MLP_H];                        // kept in VGPRs (constant-indexed, no occ bound)
#pragma unroll
  for (int kk = 0; kk < MLP_H; ++kk) w2c[kk] = w2[kk * HID + lane];
  const float b2j = b2[lane];
  const float weak = w1[128 * MLP_H + k];
  const float a1k = coef1[k], c1k = coef1[MLP_H + k];
  float sj = 0.f, qj = 0.f;
  const int wslot = blockIdx.x * 4 + (threadIdx.x >> 6);
  for (int wid = wslot; wid < N_NODES; wid += GSB * 4) {
    const int start = row_start[wid], end = row_start[wid + 1];
    float aggj = 0.f;
    if (end > start) {
      const float Pk = P[(size_t)wid * MLP_H + k];
      const int rounds = (end - start + 1) >> 1;
      int cl = min(start + half, end - 1);
      int srcc = srcS[cl];
      float eac = eaS[cl];
      float qv = Q[(size_t)srcc * MLP_H + k];
      for (int r = 0; r < rounds; ++r) {
        const bool second = (start + 2*r + 1) < end;  // wave-uniform
        float z = Pk + qv + eac * weak;
        float m = fmaxf(fmaf(a1k, z, c1k), 0.f);
        if (r + 1 < rounds) {
          int cn = min(start + 2*(r+1) + half, end - 1);
          int sn = srcS[cn];
          eac = eaS[cn];
          qv = Q[(size_t)sn * MLP_H + k];
        }
        float v0a = b2j, v0b = 0.f, v1a = b2j, v1b = 0.f;
#pragma unroll
        for (int kk = 0; kk < MLP_H; kk += 2) {
          v0a = fmaf(bcast_lane(m, kk),        w2c[kk],   v0a);
          v0b = fmaf(bcast_lane(m, kk+1),      w2c[kk+1], v0b);
          v1a = fmaf(shfl_bcast(m, 32+kk),     w2c[kk],   v1a);
          v1b = fmaf(shfl_bcast(m, 32+kk+1),   w2c[kk+1], v1b);
        }
        float v0 = fmaxf(v0a + v0b, 0.f);
        aggj += v0; sj += v0; qj = fmaf(v0, v0, qj);
        if (second) {
          float v1 = fmaxf(v1a + v1b, 0.f);
          aggj += v1; sj += v1; qj = fmaf(v1, v1, qj);
        }
      }
    }
    agg[(size_t)wid * HID + lane] = aggj;
  }
  __shared__ float ls[4][HID], lq[4][HID];
  const int w = threadIdx.x >> 6;
  ls[w][lane] = sj; lq[w][lane] = qj;
  __syncthreads();
  const int t = threadIdx.x;
  if (t < HID)
    unsafeAtomicAdd(&gstat[t], ls[0][t] + ls[1][t] + ls[2][t] + ls[3][t]);
  else if (t < 2*HID)
    unsafeAtomicAdd(&gstat[t], lq[0][t-HID] + lq[1][t-HID] + lq[2][t-HID] + lq[3][t-HID]);
}

// -------------------- update stage 1 + zu1 stats --------------------
__global__ __launch_bounds__(TPB) void k_upd1(const float* __restrict__ h,
                                              const float* __restrict__ agg,
                                              const int* __restrict__ deg,
                                              const float* __restrict__ coef2, // a[64]|c[64]
                                              const float* __restrict__ w1,
                                              const float* __restrict__ b1,
                                              float* __restrict__ zu1,
                                              float* __restrict__ gstat) {
  int i = blockIdx.x * TPB + threadIdx.x;
  bool valid = i < N_NODES;
  float acc[MLP_H];
#pragma unroll
  for (int j = 0; j < MLP_H; ++j) acc[j] = 0.f;
  if (valid) {
#pragma unroll
    for (int j = 0; j < MLP_H; ++j) acc[j] = b1[j];
    const float4* hp = reinterpret_cast<const float4*>(h + (size_t)i * HID);
#pragma unroll 2
    for (int k4 = 0; k4 < 16; ++k4) {
      float4 a = hp[k4];
      const float* wr = w1 + (k4*4) * MLP_H;
#pragma unroll
      for (int j = 0; j < MLP_H; ++j)
        acc[j] += a.x*wr[j] + a.y*wr[MLP_H+j] + a.z*wr[2*MLP_H+j] + a.w*wr[3*MLP_H+j];
    }
    float degf = (float)deg[i];
    const float4* ap = reinterpret_cast<const float4*>(agg + (size_t)i * HID);
#pragma unroll 2
    for (int k4 = 0; k4 < 16; ++k4) {
      float4 g4 = ap[k4];
      int k = k4*4;
      float a0 = coef2[k]  *g4.x + coef2[HID+k]  *degf;
      float a1 = coef2[k+1]*g4.y + coef2[HID+k+1]*degf;
      float a2 = coef2[k+2]*g4.z + coef2[HID+k+2]*degf;
      float a3 = coef2[k+3]*g4.w + coef2[HID+k+3]*degf;
      const float* wr = w1 + (64 + k) * MLP_H;
#pragma unroll
      for (int j = 0; j < MLP_H; ++j)
        acc[j] += a0*wr[j] + a1*wr[MLP_H+j] + a2*wr[2*MLP_H+j] + a3*wr[3*MLP_H+j];
    }
    float4* zp = reinterpret_cast<float4*>(zu1 + (size_t)i * MLP_H);
#pragma unroll
    for (int c = 0; c < MLP_H/4; ++c) {
      float4 o = {acc[4*c], acc[4*c+1], acc[4*c+2], acc[4*c+3]};
      zp[c] = o;
    }
  }
  // stats epilogue (invalid threads contribute zeros)
  int lane = threadIdx.x & 63;
  float ks = 0.f, kq = 0.f;
#pragma unroll
  for (int j = 0; j < MLP_H; ++j) {
    float sv = wsum(acc[j]);
    float qv = wsum(acc[j]*acc[j]);
    if (lane == j) { ks = sv; kq = qv; }
  }
  __shared__ float ls[4][MLP_H], lq[4][MLP_H];
  int w = threadIdx.x >> 6;
  if (lane < MLP_H) { ls[w][lane] = ks; lq[w][lane] = kq; }
  __syncthreads();
  int t = threadIdx.x;
  if (t < MLP_H)
    unsafeAtomicAdd(&gstat[t], ls[0][t] + ls[1][t] + ls[2][t] + ls[3][t]);
  else if (t < 2*MLP_H)
    unsafeAtomicAdd(&gstat[t], lq[0][t-MLP_H] + lq[1][t-MLP_H] + lq[2][t-MLP_H] + lq[3][t-MLP_H]);
}

// -------------------- update stage 2 + tu stats --------------------
__global__ __launch_bounds__(TPB) void k_upd2(const float* __restrict__ zu1,
                                              const float* __restrict__ cf,   // a[32]|c[32]
                                              const float* __restrict__ w2,
                                              const float* __restrict__ b2,
                                              float* __restrict__ tu,
                                              float* __restrict__ gstat) {
  int i = blockIdx.x * TPB + threadIdx.x;
  bool valid = i < N_NODES;
  float m1[MLP_H];
#pragma unroll
  for (int kk = 0; kk < MLP_H; ++kk) m1[kk] = 0.f;
  if (valid) {
    const float4* zp = reinterpret_cast<const float4*>(zu1 + (size_t)i * MLP_H);
#pragma unroll
    for (int c = 0; c < MLP_H/4; ++c) {
      float4 z = zp[c];
      int kk = 4*c;
      m1[kk]   = fmaxf(cf[kk]  *z.x + cf[MLP_H+kk],   0.f);
      m1[kk+1] = fmaxf(cf[kk+1]*z.y + cf[MLP_H+kk+1], 0.f);
      m1[kk+2] = fmaxf(cf[kk+2]*z.z + cf[MLP_H+kk+2], 0.f);
      m1[kk+3] = fmaxf(cf[kk+3]*z.w + cf[MLP_H+kk+3], 0.f);
    }
  }
  int lane = threadIdx.x & 63;
  float ks = 0.f, kq = 0.f;
#pragma unroll 2
  for (int j4 = 0; j4 < HID/4; ++j4) {
    float tv[4];
#pragma unroll
    for (int c = 0; c < 4; ++c) {
      int j = j4*4 + c;
      float v = 0.f;
      if (valid) {
        v = b2[j];
#pragma unroll
        for (int kk = 0; kk < MLP_H; ++kk) v += m1[kk] * w2[kk*HID + j];
        v = fmaxf(v, 0.f);
      }
      tv[c] = v;
      float sv = wsum(v);
      float qv = wsum(v*v);
      if (lane == j) { ks = sv; kq = qv; }
    }
    if (valid) {
      float4 o = {tv[0], tv[1], tv[2], tv[3]};
      *reinterpret_cast<float4*>(tu + (size_t)i * HID + j4*4) = o;
    }
  }
  __shared__ float ls[4][HID], lq[4][HID];
  int w = threadIdx.x >> 6;
  ls[w][lane] = ks; lq[w][lane] = kq;
  __syncthreads();
  int t = threadIdx.x;
  if (t < HID)
    unsafeAtomicAdd(&gstat[t], ls[0][t] + ls[1][t] + ls[2][t] + ls[3][t]);
  else if (t < 2*HID)
    unsafeAtomicAdd(&gstat[t], lq[0][t-HID] + lq[1][t-HID] + lq[2][t-HID] + lq[3][t-HID]);
}

// -------------------- residual --------------------
__global__ __launch_bounds__(TPB) void k_resid(float* __restrict__ h,
                                               const float* __restrict__ tu,
                                               const float* __restrict__ cf) { // a[64]|c[64]
  int idx = blockIdx.x * TPB + threadIdx.x;
  if (idx >= N_NODES * (HID/4)) return;
  int j0 = (idx & (HID/4 - 1)) * 4;
  float4 hv = reinterpret_cast<const float4*>(h)[idx];
  float4 tv = reinterpret_cast<const float4*>(tu)[idx];
  float4 a = *reinterpret_cast<const float4*>(cf + j0);
  float4 c = *reinterpret_cast<const float4*>(cf + HID + j0);
  hv.x += a.x*tv.x + c.x;
  hv.y += a.y*tv.y + c.y;
  hv.z += a.z*tv.z + c.z;
  hv.w += a.w*tv.w + c.w;
  reinterpret_cast<float4*>(h)[idx] = hv;
}

// -------------------- BN coefficients --------------------
__global__ void k_coef(const float* __restrict__ gstat, int nfeat, float invcnt,
                       const float* __restrict__ g, const float* __restrict__ be,
                       float* __restrict__ coef) {
  int j = threadIdx.x;
  if (j >= nfeat) return;
  float mu = gstat[j] * invcnt;
  float var = fmaxf(gstat[nfeat + j] * invcnt - mu*mu, 0.f);
  float r = rsqrtf(var + EPS);
  float a = g[j] * r;
  coef[j] = a;
  coef[nfeat + j] = be[j] - a * mu;
}

// -------------------- pool + head --------------------
__global__ __launch_bounds__(TPB) void k_pool_head(const float* __restrict__ h,
                                                   const int* __restrict__ batch,
                                                   const float* __restrict__ ow,
                                                   const float* __restrict__ ob,
                                                   float* __restrict__ out) {
  int g = blockIdx.x;
  int lo = 0, hi = N_NODES;
  while (lo < hi) { int mid = (lo+hi) >> 1; if (batch[mid] < g) lo = mid+1; else hi = mid; }
  int start = lo;
  lo = start; hi = N_NODES;
  while (lo < hi) { int mid = (lo+hi) >> 1; if (batch[mid] < g+1) lo = mid+1; else hi = mid; }
  int end = lo;
  int j = threadIdx.x & 63;
  int sub = threadIdx.x >> 6;
  float acc = 0.f;
  for (int n = start + sub; n < end; n += 4) acc += h[(size_t)n*HID + j];
  __shared__ float red[TPB];
  red[threadIdx.x] = acc;
  __syncthreads();
  if (threadIdx.x < 64) {
    float s = red[threadIdx.x] + red[64+threadIdx.x] + red[128+threadIdx.x] + red[192+threadIdx.x];
    float cnt = (float)(end - start);
    float pooled = s / fmaxf(cnt, 1.0f);
    float v = pooled * ow[threadIdx.x];
    v = wsum(v);
    if (threadIdx.x == 0) out[g] = fmaxf(v + ob[0], 0.f);
  }
}

// -------------------- launch --------------------
extern "C" void kernel_launch(void* const* d_in, const int* in_sizes, int n_in,
                              void* d_out, int out_size, void* d_ws, size_t ws_size,
                              hipStream_t stream) {
  const float* x       = (const float*)d_in[0];
  const int*   ei      = (const int*)  d_in[1];
  const float* ea      = (const float*)d_in[2];
  const int*   batch   = (const int*)  d_in[3];
  const float* lin_w   = (const float*)d_in[4];
  const float* lin_b   = (const float*)d_in[5];
  const float* msg_w1  = (const float*)d_in[6];
  const float* msg_b1  = (const float*)d_in[7];
  const float* msg_g1  = (const float*)d_in[8];
  const float* msg_be1 = (const float*)d_in[9];
  const float* msg_w2  = (const float*)d_in[10];
  const float* msg_b2  = (const float*)d_in[11];
  const float* msg_g2  = (const float*)d_in[12];
  const float* msg_be2 = (const float*)d_in[13];
  const float* upd_w1  = (const float*)d_in[14];
  const float* upd_b1  = (const float*)d_in[15];
  const float* upd_g1  = (const float*)d_in[16];
  const float* upd_be1 = (const float*)d_in[17];
  const float* upd_w2  = (const float*)d_in[18];
  const float* upd_b2  = (const float*)d_in[19];
  const float* upd_g2  = (const float*)d_in[20];
  const float* upd_be2 = (const float*)d_in[21];
  const float* out_w   = (const float*)d_in[22];
  const float* out_b   = (const float*)d_in[23];
  float* out = (float*)d_out;

  float* W     = (float*)d_ws;
  float* h     = W;                       // 6,400,000
  float* P     = W + 6400000;             // 3,200,000
  float* Qb    = W + 9600000;             // 3,200,000
  float* agg   = W + 12800000;            // 6,400,000
  float* zu1   = W + 19200000;            // 3,200,000
  float* tu    = W + 22400000;            // 6,400,000
  float* eaS   = W + 28800000;            // 800,000
  float* stats = W + 29600000;            // 3*384
  float* coefs = W + 29601152;            // 3*384
  int*   ib    = (int*)(W + 29602304);
  int* deg       = ib;                    // 100,000
  int* row_start = ib + 100000;           // 100,001
  int* cursor    = ib + 200002;           // 100,000
  int* srcS      = ib + 300002;           // 800,000
  int* partials  = ib + 1100002;          // NCHUNK

  hipMemsetAsync(stats, 0, 3*384*sizeof(float), stream);
  hipMemsetAsync(deg, 0, N_NODES*sizeof(int), stream);

  // CSR build
  k_deg<<<N_EDGES/TPB, TPB, 0, stream>>>(ei, deg);
  k_scan_part<<<NCHUNK, SCAN_B, 0, stream>>>(deg, partials);
  k_scan_mid<<<1, 1, 0, stream>>>(partials, row_start);
  k_scan_fin<<<NCHUNK, SCAN_B, 0, stream>>>(deg, partials, row_start, cursor);
  k_fill<<<N_EDGES/TPB, TPB, 0, stream>>>(ei, ea, cursor, srcS, eaS);

  k_lin_in<<<(N_NODES+TPB-1)/TPB, TPB, 0, stream>>>(x, lin_w, lin_b, h);

  const int NODE_BLKS = (N_NODES + TPB - 1) / TPB;       // 391

  for (int l = 0; l < 3; ++l) {
    const float* mw1 = msg_w1 + (size_t)l*129*MLP_H;
    const float* mb1 = msg_b1 + l*MLP_H;
    const float* mg1 = msg_g1 + l*MLP_H;
    const float* mbe1= msg_be1 + l*MLP_H;
    const float* mw2 = msg_w2 + (size_t)l*MLP_H*HID;
    const float* mb2 = msg_b2 + l*HID;
    const float* mg2 = msg_g2 + l*HID;
    const float* mbe2= msg_be2 + l*HID;
    const float* uw1 = upd_w1 + (size_t)l*128*MLP_H;
    const float* ub1 = upd_b1 + l*MLP_H;
    const float* ug1 = upd_g1 + l*MLP_H;
    const float* ube1= upd_be1 + l*MLP_H;
    const float* uw2 = upd_w2 + (size_t)l*MLP_H*HID;
    const float* ub2 = upd_b2 + l*HID;
    const float* ug2 = upd_g2 + l*HID;
    const float* ube2= upd_be2 + l*HID;
    float* st = stats + l*384;
    float* cf = coefs + l*384;

    k_pq<<<NODE_BLKS, TPB, 0, stream>>>(h, mw1, mb1, P, Qb);
    k_zstats<<<GSB, TPB, 0, stream>>>(P, Qb, srcS, eaS, row_start, mw1, st);
    k_coef<<<1, 64, 0, stream>>>(st, MLP_H, 1.f/N_EDGES, mg1, mbe1, cf);
    k_msg<<<GSB, TPB, 0, stream>>>(P, Qb, srcS, eaS, row_start, mw1, cf, mw2, mb2,
                                   agg, st+64);
    k_coef<<<1, 64, 0, stream>>>(st+64, HID, 1.f/N_EDGES, mg2, mbe2, cf+64);
    k_upd1<<<NODE_BLKS, TPB, 0, stream>>>(h, agg, deg, cf+64, uw1, ub1, zu1, st+192);
    k_coef<<<1, 64, 0, stream>>>(st+192, MLP_H, 1.f/N_NODES, ug1, ube1, cf+192);
    k_upd2<<<NODE_BLKS, TPB, 0, stream>>>(zu1, cf+192, uw2, ub2, tu, st+256);
    k_coef<<<1, 64, 0, stream>>>(st+256, HID, 1.f/N_NODES, ug2, ube2, cf+256);
    k_resid<<<(N_NODES*(HID/4)+TPB-1)/TPB, TPB, 0, stream>>>(h, tu, cf+256);
  }

  k_pool_head<<<NUM_GRAPHS, TPB, 0, stream>>>(h, batch, out_w, out_b, out);
}

// Round 4
// 1260.397 us; speedup vs baseline: 7.0221x; 1.1669x over previous
//
#include <hip/hip_runtime.h>
#include <hip/hip_bf16.h>

#define N_NODES   100000
#define N_EDGES   800000
#define NUM_GRAPHS 512
#define IN_DIM    16
#define HID       64
#define MLP_H     32
#define EPS       1e-5f
#define TPB       256
#define SCAN_B    1024
#define NCHUNK    ((N_NODES + SCAN_B - 1) / SCAN_B)   // 98
#define GSB       2048
#define NWAVES    (GSB * 4)                           // 8192
#define PER_W     ((N_EDGES + NWAVES - 1) / NWAVES)   // 98 edges per wave

__device__ __forceinline__ float bcast_lane(float v, int kk) {
  return __int_as_float(__builtin_amdgcn_readlane(__float_as_int(v), kk));
}
__device__ __forceinline__ float wsum(float v) {
  v += __shfl_xor(v, 1, 64);
  v += __shfl_xor(v, 2, 64);
  v += __shfl_xor(v, 4, 64);
  v += __shfl_xor(v, 8, 64);
  v += __shfl_xor(v, 16, 64);
  v += __shfl_xor(v, 32, 64);
  return v;
}
__device__ __forceinline__ int lbound(const int* __restrict__ rs, int key) {
  int lo = 0, hi = N_NODES;
  while (lo < hi) { int m = (lo + hi) >> 1; if (rs[m] < key) lo = m + 1; else hi = m; }
  return lo;
}

// -------------------- CSR build --------------------
__global__ __launch_bounds__(TPB) void k_deg(const int* __restrict__ ei, int* __restrict__ deg) {
  int e = blockIdx.x * TPB + threadIdx.x;
  if (e < N_EDGES) atomicAdd(&deg[ei[N_EDGES + e]], 1);
}

__global__ __launch_bounds__(SCAN_B) void k_scan_part(const int* __restrict__ deg,
                                                      int* __restrict__ partials) {
  __shared__ int red[SCAN_B];
  int i = blockIdx.x * SCAN_B + threadIdx.x;
  red[threadIdx.x] = (i < N_NODES) ? deg[i] : 0;
  __syncthreads();
  for (int off = SCAN_B / 2; off > 0; off >>= 1) {
    if (threadIdx.x < off) red[threadIdx.x] += red[threadIdx.x + off];
    __syncthreads();
  }
  if (threadIdx.x == 0) partials[blockIdx.x] = red[0];
}

__global__ void k_scan_mid(int* __restrict__ partials, int* __restrict__ row_start) {
  int run = 0;
  for (int b = 0; b < NCHUNK; ++b) { int t = partials[b]; partials[b] = run; run += t; }
  row_start[N_NODES] = run;  // == N_EDGES
}

__global__ __launch_bounds__(SCAN_B) void k_scan_fin(const int* __restrict__ deg,
                                                     const int* __restrict__ partials,
                                                     int* __restrict__ row_start,
                                                     int* __restrict__ cursor) {
  __shared__ int buf[2][SCAN_B];
  int t = threadIdx.x, i = blockIdx.x * SCAN_B + t;
  int v = (i < N_NODES) ? deg[i] : 0;
  buf[0][t] = v;
  __syncthreads();
  int cur = 0;
  for (int off = 1; off < SCAN_B; off <<= 1) {
    int nv = buf[cur][t] + ((t >= off) ? buf[cur][t - off] : 0);
    buf[cur ^ 1][t] = nv; cur ^= 1;
    __syncthreads();
  }
  if (i < N_NODES) {
    int excl = buf[cur][t] - v + partials[blockIdx.x];
    row_start[i] = excl;
    cursor[i] = excl;
  }
}

__global__ __launch_bounds__(TPB) void k_fill(const int* __restrict__ ei,
                                              const float* __restrict__ ea,
                                              int* __restrict__ cursor,
                                              int* __restrict__ srcS,
                                              int* __restrict__ dstS,
                                              float* __restrict__ eaS) {
  int e = blockIdx.x * TPB + threadIdx.x;
  if (e >= N_EDGES) return;
  int dst = ei[N_EDGES + e];
  int pos = atomicAdd(&cursor[dst], 1);
  srcS[pos] = ei[e];
  dstS[pos] = dst;
  eaS[pos] = ea[e];
}

// -------------------- input projection --------------------
__global__ __launch_bounds__(TPB) void k_lin_in(const float* __restrict__ x,
                                                const float* __restrict__ w,
                                                const float* __restrict__ b,
                                                float* __restrict__ h) {
  int i = blockIdx.x * TPB + threadIdx.x;
  if (i >= N_NODES) return;
  float xi[IN_DIM];
  const float4* xp = reinterpret_cast<const float4*>(x + (size_t)i * IN_DIM);
#pragma unroll
  for (int q = 0; q < 4; ++q) {
    float4 v = xp[q];
    xi[4*q] = v.x; xi[4*q+1] = v.y; xi[4*q+2] = v.z; xi[4*q+3] = v.w;
  }
  float4* hp = reinterpret_cast<float4*>(h + (size_t)i * HID);
#pragma unroll
  for (int j4 = 0; j4 < HID/4; ++j4) {
    float o[4];
#pragma unroll
    for (int c = 0; c < 4; ++c) {
      int j = j4*4 + c;
      float acc = b[j];
#pragma unroll
      for (int k = 0; k < IN_DIM; ++k) acc += xi[k] * w[k*HID + j];
      o[c] = acc;
    }
    float4 ov = {o[0], o[1], o[2], o[3]};
    hp[j4] = ov;
  }
}

// -------------------- per-node msg projections: P = h@W1[0:64]+b1, Q = h@W1[64:128] ----
__global__ __launch_bounds__(TPB) void k_pq(const float* __restrict__ h,
                                            const float* __restrict__ w1,
                                            const float* __restrict__ b1,
                                            float* __restrict__ P,
                                            float* __restrict__ Q) {
  int i = blockIdx.x * TPB + threadIdx.x;
  if (i >= N_NODES) return;
  float p[MLP_H], q[MLP_H];
#pragma unroll
  for (int j = 0; j < MLP_H; ++j) { p[j] = b1[j]; q[j] = 0.f; }
  const float4* hp = reinterpret_cast<const float4*>(h + (size_t)i * HID);
#pragma unroll 2
  for (int k4 = 0; k4 < 16; ++k4) {
    float4 a = hp[k4];
    const float* wp = w1 + (k4*4) * MLP_H;
    const float* wq = w1 + (64 + k4*4) * MLP_H;
#pragma unroll
    for (int j = 0; j < MLP_H; ++j) {
      p[j] += a.x*wp[j] + a.y*wp[MLP_H+j] + a.z*wp[2*MLP_H+j] + a.w*wp[3*MLP_H+j];
      q[j] += a.x*wq[j] + a.y*wq[MLP_H+j] + a.z*wq[2*MLP_H+j] + a.w*wq[3*MLP_H+j];
    }
  }
  float4* pp = reinterpret_cast<float4*>(P + (size_t)i * MLP_H);
  float4* qp = reinterpret_cast<float4*>(Q + (size_t)i * MLP_H);
#pragma unroll
  for (int c = 0; c < MLP_H/4; ++c) {
    float4 pv = {p[4*c], p[4*c+1], p[4*c+2], p[4*c+3]};
    float4 qv = {q[4*c], q[4*c+1], q[4*c+2], q[4*c+3]};
    pp[c] = pv; qp[c] = qv;
  }
}

// -------------------- pass 1: gather + z compute + z1 store + BN1 stats ---------------
// Edge-indexed, balanced (PER_W contiguous edges per wave), half-wave split,
// 1-round-ahead prefetch. z1[e*32+k] written for every edge.
__global__ __launch_bounds__(TPB) void k_gather(const float* __restrict__ P,
                                                const float* __restrict__ Q,
                                                const int* __restrict__ srcS,
                                                const int* __restrict__ dstS,
                                                const float* __restrict__ eaS,
                                                const float* __restrict__ w1,
                                                float* __restrict__ z1,
                                                float* __restrict__ gstat) {
  const int lane = threadIdx.x & 63;
  const int k = lane & 31;
  const int half = lane >> 5;
  const float weak = w1[128 * MLP_H + k];
  float s = 0.f, q = 0.f;
  const int wv = blockIdx.x * 4 + (threadIdx.x >> 6);
  const int c0 = wv * PER_W;
  const int c1 = min(c0 + PER_W, N_EDGES);
  if (c0 < N_EDGES) {
    const int rounds = (c1 - c0 + 1) >> 1;
    const int e0 = c0 + half;
    int ec = min(e0, c1 - 1);
    bool vc = e0 < c1;
    float ac = eaS[ec];
    float qv = Q[(size_t)srcS[ec] * MLP_H + k];
    float pv = P[(size_t)dstS[ec] * MLP_H + k];
    for (int r = 0; r < rounds; ++r) {
      const int en = e0 + 2 * (r + 1);
      const int ecn = min(en, c1 - 1);
      const bool vn = en < c1;
      // prefetch next round (clamped -> always safe)
      float an = eaS[ecn];
      float qn = Q[(size_t)srcS[ecn] * MLP_H + k];
      float pn = P[(size_t)dstS[ecn] * MLP_H + k];
      float z = pv + qv + ac * weak;
      if (vc) {
        z1[(size_t)ec * MLP_H + k] = z;
        s += z; q = fmaf(z, z, q);
      }
      qv = qn; pv = pn; ac = an; vc = vn; ec = ecn;
    }
  }
  s += __shfl_xor(s, 32, 64);
  q += __shfl_xor(q, 32, 64);
  __shared__ float ls[4][MLP_H], lq[4][MLP_H];
  const int w = threadIdx.x >> 6;
  if (lane < MLP_H) { ls[w][lane] = s; lq[w][lane] = q; }
  __syncthreads();
  const int t = threadIdx.x;
  if (t < MLP_H)
    unsafeAtomicAdd(&gstat[t], ls[0][t] + ls[1][t] + ls[2][t] + ls[3][t]);
  else if (t < 2*MLP_H)
    unsafeAtomicAdd(&gstat[t], lq[0][t-MLP_H] + lq[1][t-MLP_H] + lq[2][t-MLP_H] + lq[3][t-MLP_H]);
}

// -------------------- pass 2: linear z1 -> m1 -> t -> aggregate + t-stats -------------
// Node ranges balanced by edge count (binary search on row_start); no atomics for agg.
// BN1 coefficients computed inline per lane from raw stats.
__global__ __launch_bounds__(TPB) void k_msgdot(const float* __restrict__ z1,
                                                const int* __restrict__ rs,
                                                const float* __restrict__ gstat_in, // BN1 stats
                                                const float* __restrict__ g1,
                                                const float* __restrict__ be1,
                                                const float* __restrict__ w2,
                                                const float* __restrict__ b2,
                                                float* __restrict__ agg,
                                                float* __restrict__ gstat_out) {
  const int lane = threadIdx.x & 63;
  const int k = lane & 31;
  const int half = lane >> 5;
  // inline BN1 coefficients for feature k
  const float mu1 = gstat_in[k] * (1.f / N_EDGES);
  const float var1 = fmaxf(gstat_in[MLP_H + k] * (1.f / N_EDGES) - mu1 * mu1, 0.f);
  const float a1k = g1[k] * rsqrtf(var1 + EPS);
  const float c1k = be1[k] - a1k * mu1;
  float w2c[MLP_H];
#pragma unroll
  for (int kk = 0; kk < MLP_H; ++kk) w2c[kk] = w2[kk * HID + lane];
  const float b2j = b2[lane];
  const int wv = blockIdx.x * 4 + (threadIdx.x >> 6);
  const int key0 = min(wv * PER_W, N_EDGES);
  const int key1 = min((wv + 1) * PER_W, N_EDGES);
  const int n0 = lbound(rs, key0);
  const int n1 = (wv == NWAVES - 1) ? N_NODES : lbound(rs, key1);
  float sj = 0.f, qj = 0.f;
  for (int n = n0; n < n1; ++n) {
    const int start = rs[n], end = rs[n + 1];
    float aggj = 0.f;
    if (end > start) {
      const int rounds = (end - start + 1) >> 1;
      const int e0 = start + half;
      int ec = min(e0, end - 1);
      float zc = z1[(size_t)ec * MLP_H + k];
      for (int r = 0; r < rounds; ++r) {
        const int en = min(e0 + 2 * (r + 1), end - 1);
        float zn = z1[(size_t)en * MLP_H + k];            // prefetch next (linear)
        const bool second = (start + 2 * r + 1) < end;    // wave-uniform
        float m = fmaxf(fmaf(a1k, zc, c1k), 0.f);
        float mB = __shfl_xor(m, 32, 64);  // lanes 0-31 now see edge-B's m1
        float v0a = b2j, v0b = 0.f, v1a = b2j, v1b = 0.f;
#pragma unroll
        for (int kk = 0; kk < MLP_H; kk += 2) {
          v0a = fmaf(bcast_lane(m,  kk),     w2c[kk],   v0a);
          v0b = fmaf(bcast_lane(m,  kk + 1), w2c[kk+1], v0b);
          v1a = fmaf(bcast_lane(mB, kk),     w2c[kk],   v1a);
          v1b = fmaf(bcast_lane(mB, kk + 1), w2c[kk+1], v1b);
        }
        float v0 = fmaxf(v0a + v0b, 0.f);
        aggj += v0; sj += v0; qj = fmaf(v0, v0, qj);
        if (second) {
          float v1 = fmaxf(v1a + v1b, 0.f);
          aggj += v1; sj += v1; qj = fmaf(v1, v1, qj);
        }
        zc = zn;
      }
    }
    agg[(size_t)n * HID + lane] = aggj;
  }
  __shared__ float ls[4][HID], lq[4][HID];
  const int w = threadIdx.x >> 6;
  ls[w][lane] = sj; lq[w][lane] = qj;
  __syncthreads();
  const int t = threadIdx.x;
  if (t < HID)
    unsafeAtomicAdd(&gstat_out[t], ls[0][t] + ls[1][t] + ls[2][t] + ls[3][t]);
  else if (t < 2*HID)
    unsafeAtomicAdd(&gstat_out[t], lq[0][t-HID] + lq[1][t-HID] + lq[2][t-HID] + lq[3][t-HID]);
}

// -------------------- update stage 1 + zu1 stats (BN2 coefs inline via LDS) -----------
__global__ __launch_bounds__(TPB) void k_upd1(const float* __restrict__ h,
                                              const float* __restrict__ agg,
                                              const int* __restrict__ deg,
                                              const float* __restrict__ gstat_in, // t stats (E count)
                                              const float* __restrict__ g2,
                                              const float* __restrict__ be2,
                                              const float* __restrict__ w1,
                                              const float* __restrict__ b1,
                                              float* __restrict__ zu1,
                                              float* __restrict__ gstat_out) {
  __shared__ float sa[HID], sc[HID];
  {
    int t = threadIdx.x;
    if (t < HID) {
      float mu = gstat_in[t] * (1.f / N_EDGES);
      float var = fmaxf(gstat_in[HID + t] * (1.f / N_EDGES) - mu * mu, 0.f);
      float a = g2[t] * rsqrtf(var + EPS);
      sa[t] = a; sc[t] = be2[t] - a * mu;
    }
  }
  __syncthreads();
  int i = blockIdx.x * TPB + threadIdx.x;
  bool valid = i < N_NODES;
  float acc[MLP_H];
#pragma unroll
  for (int j = 0; j < MLP_H; ++j) acc[j] = 0.f;
  if (valid) {
#pragma unroll
    for (int j = 0; j < MLP_H; ++j) acc[j] = b1[j];
    const float4* hp = reinterpret_cast<const float4*>(h + (size_t)i * HID);
#pragma unroll 2
    for (int k4 = 0; k4 < 16; ++k4) {
      float4 a = hp[k4];
      const float* wr = w1 + (k4*4) * MLP_H;
#pragma unroll
      for (int j = 0; j < MLP_H; ++j)
        acc[j] += a.x*wr[j] + a.y*wr[MLP_H+j] + a.z*wr[2*MLP_H+j] + a.w*wr[3*MLP_H+j];
    }
    float degf = (float)deg[i];
    const float4* ap = reinterpret_cast<const float4*>(agg + (size_t)i * HID);
#pragma unroll 2
    for (int k4 = 0; k4 < 16; ++k4) {
      float4 g4 = ap[k4];
      int k = k4*4;
      float a0 = sa[k]  *g4.x + sc[k]  *degf;
      float a1 = sa[k+1]*g4.y + sc[k+1]*degf;
      float a2 = sa[k+2]*g4.z + sc[k+2]*degf;
      float a3 = sa[k+3]*g4.w + sc[k+3]*degf;
      const float* wr = w1 + (64 + k) * MLP_H;
#pragma unroll
      for (int j = 0; j < MLP_H; ++j)
        acc[j] += a0*wr[j] + a1*wr[MLP_H+j] + a2*wr[2*MLP_H+j] + a3*wr[3*MLP_H+j];
    }
    float4* zp = reinterpret_cast<float4*>(zu1 + (size_t)i * MLP_H);
#pragma unroll
    for (int c = 0; c < MLP_H/4; ++c) {
      float4 o = {acc[4*c], acc[4*c+1], acc[4*c+2], acc[4*c+3]};
      zp[c] = o;
    }
  }
  int lane = threadIdx.x & 63;
  float ks = 0.f, kq = 0.f;
#pragma unroll
  for (int j = 0; j < MLP_H; ++j) {
    float sv = wsum(acc[j]);
    float qv = wsum(acc[j]*acc[j]);
    if (lane == j) { ks = sv; kq = qv; }
  }
  __shared__ float ls[4][MLP_H], lq[4][MLP_H];
  int w = threadIdx.x >> 6;
  if (lane < MLP_H) { ls[w][lane] = ks; lq[w][lane] = kq; }
  __syncthreads();
  int t = threadIdx.x;
  if (t < MLP_H)
    unsafeAtomicAdd(&gstat_out[t], ls[0][t] + ls[1][t] + ls[2][t] + ls[3][t]);
  else if (t < 2*MLP_H)
    unsafeAtomicAdd(&gstat_out[t], lq[0][t-MLP_H] + lq[1][t-MLP_H] + lq[2][t-MLP_H] + lq[3][t-MLP_H]);
}

// -------------------- update stage 2 + tu stats (BNu1 coefs inline via LDS) -----------
__global__ __launch_bounds__(TPB) void k_upd2(const float* __restrict__ zu1,
                                              const float* __restrict__ gstat_in, // zu1 stats (N count)
                                              const float* __restrict__ gu1,
                                              const float* __restrict__ beu1,
                                              const float* __restrict__ w2,
                                              const float* __restrict__ b2,
                                              float* __restrict__ tu,
                                              float* __restrict__ gstat_out) {
  __shared__ float sa[MLP_H], sc[MLP_H];
  {
    int t = threadIdx.x;
    if (t < MLP_H) {
      float mu = gstat_in[t] * (1.f / N_NODES);
      float var = fmaxf(gstat_in[MLP_H + t] * (1.f / N_NODES) - mu * mu, 0.f);
      float a = gu1[t] * rsqrtf(var + EPS);
      sa[t] = a; sc[t] = beu1[t] - a * mu;
    }
  }
  __syncthreads();
  int i = blockIdx.x * TPB + threadIdx.x;
  bool valid = i < N_NODES;
  float m1[MLP_H];
#pragma unroll
  for (int kk = 0; kk < MLP_H; ++kk) m1[kk] = 0.f;
  if (valid) {
    const float4* zp = reinterpret_cast<const float4*>(zu1 + (size_t)i * MLP_H);
#pragma unroll
    for (int c = 0; c < MLP_H/4; ++c) {
      float4 z = zp[c];
      int kk = 4*c;
      m1[kk]   = fmaxf(sa[kk]  *z.x + sc[kk],   0.f);
      m1[kk+1] = fmaxf(sa[kk+1]*z.y + sc[kk+1], 0.f);
      m1[kk+2] = fmaxf(sa[kk+2]*z.z + sc[kk+2], 0.f);
      m1[kk+3] = fmaxf(sa[kk+3]*z.w + sc[kk+3], 0.f);
    }
  }
  int lane = threadIdx.x & 63;
  float ks = 0.f, kq = 0.f;
#pragma unroll 2
  for (int j4 = 0; j4 < HID/4; ++j4) {
    float tv[4];
#pragma unroll
    for (int c = 0; c < 4; ++c) {
      int j = j4*4 + c;
      float v = 0.f;
      if (valid) {
        v = b2[j];
#pragma unroll
        for (int kk = 0; kk < MLP_H; ++kk) v += m1[kk] * w2[kk*HID + j];
        v = fmaxf(v, 0.f);
      }
      tv[c] = v;
      float sv = wsum(v);
      float qv = wsum(v*v);
      if (lane == j) { ks = sv; kq = qv; }
    }
    if (valid) {
      float4 o = {tv[0], tv[1], tv[2], tv[3]};
      *reinterpret_cast<float4*>(tu + (size_t)i * HID + j4*4) = o;
    }
  }
  __shared__ float ls[4][HID], lq[4][HID];
  int w = threadIdx.x >> 6;
  ls[w][lane] = ks; lq[w][lane] = kq;
  __syncthreads();
  int t = threadIdx.x;
  if (t < HID)
    unsafeAtomicAdd(&gstat_out[t], ls[0][t] + ls[1][t] + ls[2][t] + ls[3][t]);
  else if (t < 2*HID)
    unsafeAtomicAdd(&gstat_out[t], lq[0][t-HID] + lq[1][t-HID] + lq[2][t-HID] + lq[3][t-HID]);
}

// -------------------- residual (BNu2 coefs inline via LDS) --------------------
__global__ __launch_bounds__(TPB) void k_resid(float* __restrict__ h,
                                               const float* __restrict__ tu,
                                               const float* __restrict__ gstat_in, // tu stats (N count)
                                               const float* __restrict__ gu2,
                                               const float* __restrict__ beu2) {
  __shared__ float sa[HID], sc[HID];
  {
    int t = threadIdx.x;
    if (t < HID) {
      float mu = gstat_in[t] * (1.f / N_NODES);
      float var = fmaxf(gstat_in[HID + t] * (1.f / N_NODES) - mu * mu, 0.f);
      float a = gu2[t] * rsqrtf(var + EPS);
      sa[t] = a; sc[t] = beu2[t] - a * mu;
    }
  }
  __syncthreads();
  int idx = blockIdx.x * TPB + threadIdx.x;
  if (idx >= N_NODES * (HID/4)) return;
  int j0 = (idx & (HID/4 - 1)) * 4;
  float4 hv = reinterpret_cast<const float4*>(h)[idx];
  float4 tv = reinterpret_cast<const float4*>(tu)[idx];
  hv.x += sa[j0]  *tv.x + sc[j0];
  hv.y += sa[j0+1]*tv.y + sc[j0+1];
  hv.z += sa[j0+2]*tv.z + sc[j0+2];
  hv.w += sa[j0+3]*tv.w + sc[j0+3];
  reinterpret_cast<float4*>(h)[idx] = hv;
}

// -------------------- pool + head --------------------
__global__ __launch_bounds__(TPB) void k_pool_head(const float* __restrict__ h,
                                                   const int* __restrict__ batch,
                                                   const float* __restrict__ ow,
                                                   const float* __restrict__ ob,
                                                   float* __restrict__ out) {
  int g = blockIdx.x;
  int lo = 0, hi = N_NODES;
  while (lo < hi) { int mid = (lo+hi) >> 1; if (batch[mid] < g) lo = mid+1; else hi = mid; }
  int start = lo;
  lo = start; hi = N_NODES;
  while (lo < hi) { int mid = (lo+hi) >> 1; if (batch[mid] < g+1) lo = mid+1; else hi = mid; }
  int end = lo;
  int j = threadIdx.x & 63;
  int sub = threadIdx.x >> 6;
  float acc = 0.f;
  for (int n = start + sub; n < end; n += 4) acc += h[(size_t)n*HID + j];
  __shared__ float red[TPB];
  red[threadIdx.x] = acc;
  __syncthreads();
  if (threadIdx.x < 64) {
    float s = red[threadIdx.x] + red[64+threadIdx.x] + red[128+threadIdx.x] + red[192+threadIdx.x];
    float cnt = (float)(end - start);
    float pooled = s / fmaxf(cnt, 1.0f);
    float v = pooled * ow[threadIdx.x];
    v = wsum(v);
    if (threadIdx.x == 0) out[g] = fmaxf(v + ob[0], 0.f);
  }
}

// -------------------- launch --------------------
extern "C" void kernel_launch(void* const* d_in, const int* in_sizes, int n_in,
                              void* d_out, int out_size, void* d_ws, size_t ws_size,
                              hipStream_t stream) {
  const float* x       = (const float*)d_in[0];
  const int*   ei      = (const int*)  d_in[1];
  const float* ea      = (const float*)d_in[2];
  const int*   batch   = (const int*)  d_in[3];
  const float* lin_w   = (const float*)d_in[4];
  const float* lin_b   = (const float*)d_in[5];
  const float* msg_w1  = (const float*)d_in[6];
  const float* msg_b1  = (const float*)d_in[7];
  const float* msg_g1  = (const float*)d_in[8];
  const float* msg_be1 = (const float*)d_in[9];
  const float* msg_w2  = (const float*)d_in[10];
  const float* msg_b2  = (const float*)d_in[11];
  const float* msg_g2  = (const float*)d_in[12];
  const float* msg_be2 = (const float*)d_in[13];
  const float* upd_w1  = (const float*)d_in[14];
  const float* upd_b1  = (const float*)d_in[15];
  const float* upd_g1  = (const float*)d_in[16];
  const float* upd_be1 = (const float*)d_in[17];
  const float* upd_w2  = (const float*)d_in[18];
  const float* upd_b2  = (const float*)d_in[19];
  const float* upd_g2  = (const float*)d_in[20];
  const float* upd_be2 = (const float*)d_in[21];
  const float* out_w   = (const float*)d_in[22];
  const float* out_b   = (const float*)d_in[23];
  float* out = (float*)d_out;

  float* W     = (float*)d_ws;
  float* h     = W;                       //  6,400,000
  float* P     = W + 6400000;             //  3,200,000
  float* Qb    = W + 9600000;             //  3,200,000
  float* agg   = W + 12800000;            //  6,400,000
  float* z1    = W + 19200000;            // 25,600,000
  float* zu1   = z1;                      //  (alias: z1 dead when written)
  float* tu    = z1 + 3200000;            //  (alias)
  float* eaS   = W + 44800000;            //    800,000
  float* stats = W + 45600000;            //  3*384
  int*   ib    = (int*)(W + 45601152);
  int* deg       = ib;                    //   100,000
  int* row_start = ib + 100000;           //   100,001
  int* cursor    = ib + 200001;           //   100,000
  int* srcS      = ib + 300001;           //   800,000
  int* dstS      = ib + 1100001;          //   800,000
  int* partials  = ib + 1900001;          //   NCHUNK

  hipMemsetAsync(stats, 0, 3*384*sizeof(float), stream);
  hipMemsetAsync(deg, 0, N_NODES*sizeof(int), stream);

  // CSR build
  k_deg<<<N_EDGES/TPB, TPB, 0, stream>>>(ei, deg);
  k_scan_part<<<NCHUNK, SCAN_B, 0, stream>>>(deg, partials);
  k_scan_mid<<<1, 1, 0, stream>>>(partials, row_start);
  k_scan_fin<<<NCHUNK, SCAN_B, 0, stream>>>(deg, partials, row_start, cursor);
  k_fill<<<N_EDGES/TPB, TPB, 0, stream>>>(ei, ea, cursor, srcS, dstS, eaS);

  k_lin_in<<<(N_NODES+TPB-1)/TPB, TPB, 0, stream>>>(x, lin_w, lin_b, h);

  const int NODE_BLKS = (N_NODES + TPB - 1) / TPB;       // 391

  for (int l = 0; l < 3; ++l) {
    const float* mw1 = msg_w1 + (size_t)l*129*MLP_H;
    const float* mb1 = msg_b1 + l*MLP_H;
    const float* mg1 = msg_g1 + l*MLP_H;
    const float* mbe1= msg_be1 + l*MLP_H;
    const float* mw2 = msg_w2 + (size_t)l*MLP_H*HID;
    const float* mb2 = msg_b2 + l*HID;
    const float* mg2 = msg_g2 + l*HID;
    const float* mbe2= msg_be2 + l*HID;
    const float* uw1 = upd_w1 + (size_t)l*128*MLP_H;
    const float* ub1 = upd_b1 + l*MLP_H;
    const float* ug1 = upd_g1 + l*MLP_H;
    const float* ube1= upd_be1 + l*MLP_H;
    const float* uw2 = upd_w2 + (size_t)l*MLP_H*HID;
    const float* ub2 = upd_b2 + l*HID;
    const float* ug2 = upd_g2 + l*HID;
    const float* ube2= upd_be2 + l*HID;
    float* st = stats + l*384;   // [0:64) BN1 | [64:192) BN2 | [192:256) BNu1 | [256:384) BNu2

    k_pq<<<NODE_BLKS, TPB, 0, stream>>>(h, mw1, mb1, P, Qb);
    k_gather<<<GSB, TPB, 0, stream>>>(P, Qb, srcS, dstS, eaS, mw1, z1, st);
    k_msgdot<<<GSB, TPB, 0, stream>>>(z1, row_start, st, mg1, mbe1, mw2, mb2, agg, st+64);
    k_upd1<<<NODE_BLKS, TPB, 0, stream>>>(h, agg, deg, st+64, mg2, mbe2, uw1, ub1, zu1, st+192);
    k_upd2<<<NODE_BLKS, TPB, 0, stream>>>(zu1, st+192, ug1, ube1, uw2, ub2, tu, st+256);
    k_resid<<<(N_NODES*(HID/4)+TPB-1)/TPB, TPB, 0, stream>>>(h, tu, st+256, ug2, ube2);
  }

  k_pool_head<<<NUM_GRAPHS, TPB, 0, stream>>>(h, batch, out_w, out_b, out);
}

// Round 5
// 1203.115 us; speedup vs baseline: 7.3564x; 1.0476x over previous
//
#include <hip/hip_runtime.h>
#include <hip/hip_bf16.h>

#define N_NODES   100000
#define N_EDGES   800000
#define NUM_GRAPHS 512
#define IN_DIM    16
#define HID       64
#define MLP_H     32
#define EPS       1e-5f
#define TPB       256
#define SCAN_B    1024
#define NCHUNK    ((N_NODES + SCAN_B - 1) / SCAN_B)   // 98
#define GSB       2048
#define NWAVES    (GSB * 4)                           // 8192
#define PER_W     ((N_EDGES + NWAVES - 1) / NWAVES)   // 98 edges per wave

using nh2 = decltype(__builtin_amdgcn_cvt_pkrtz(0.f, 0.f));  // packed 2x f16

__device__ __forceinline__ nh2 pack2(float a, float b) {
  return __builtin_amdgcn_cvt_pkrtz(a, b);
}
__device__ __forceinline__ nh2 bcast_h2(nh2 v, int l) {
  int b = __builtin_bit_cast(int, v);
  b = __builtin_amdgcn_readlane(b, l);
  return __builtin_bit_cast(nh2, b);
}
__device__ __forceinline__ float dot2acc(nh2 a, nh2 b, float c) {
#if __has_builtin(__builtin_amdgcn_fdot2)
  return __builtin_amdgcn_fdot2(a, b, c, false);
#else
  return c + (float)a.x * (float)b.x + (float)a.y * (float)b.y;
#endif
}
__device__ __forceinline__ float wsum(float v) {
  v += __shfl_xor(v, 1, 64);
  v += __shfl_xor(v, 2, 64);
  v += __shfl_xor(v, 4, 64);
  v += __shfl_xor(v, 8, 64);
  v += __shfl_xor(v, 16, 64);
  v += __shfl_xor(v, 32, 64);
  return v;
}
__device__ __forceinline__ int lbound(const int* __restrict__ rs, int key) {
  int lo = 0, hi = N_NODES;
  while (lo < hi) { int m = (lo + hi) >> 1; if (rs[m] < key) lo = m + 1; else hi = m; }
  return lo;
}

// -------------------- CSR build --------------------
__global__ __launch_bounds__(TPB) void k_deg(const int* __restrict__ ei, int* __restrict__ deg) {
  int e = blockIdx.x * TPB + threadIdx.x;
  if (e < N_EDGES) atomicAdd(&deg[ei[N_EDGES + e]], 1);
}

__global__ __launch_bounds__(SCAN_B) void k_scan_part(const int* __restrict__ deg,
                                                      int* __restrict__ partials) {
  __shared__ int red[SCAN_B];
  int i = blockIdx.x * SCAN_B + threadIdx.x;
  red[threadIdx.x] = (i < N_NODES) ? deg[i] : 0;
  __syncthreads();
  for (int off = SCAN_B / 2; off > 0; off >>= 1) {
    if (threadIdx.x < off) red[threadIdx.x] += red[threadIdx.x + off];
    __syncthreads();
  }
  if (threadIdx.x == 0) partials[blockIdx.x] = red[0];
}

__global__ void k_scan_mid(int* __restrict__ partials, int* __restrict__ row_start) {
  int run = 0;
  for (int b = 0; b < NCHUNK; ++b) { int t = partials[b]; partials[b] = run; run += t; }
  row_start[N_NODES] = run;  // == N_EDGES
}

__global__ __launch_bounds__(SCAN_B) void k_scan_fin(const int* __restrict__ deg,
                                                     const int* __restrict__ partials,
                                                     int* __restrict__ row_start,
                                                     int* __restrict__ cursor) {
  __shared__ int buf[2][SCAN_B];
  int t = threadIdx.x, i = blockIdx.x * SCAN_B + t;
  int v = (i < N_NODES) ? deg[i] : 0;
  buf[0][t] = v;
  __syncthreads();
  int cur = 0;
  for (int off = 1; off < SCAN_B; off <<= 1) {
    int nv = buf[cur][t] + ((t >= off) ? buf[cur][t - off] : 0);
    buf[cur ^ 1][t] = nv; cur ^= 1;
    __syncthreads();
  }
  if (i < N_NODES) {
    int excl = buf[cur][t] - v + partials[blockIdx.x];
    row_start[i] = excl;
    cursor[i] = excl;
  }
}

__global__ __launch_bounds__(TPB) void k_fill(const int* __restrict__ ei,
                                              const float* __restrict__ ea,
                                              int* __restrict__ cursor,
                                              int* __restrict__ srcS,
                                              int* __restrict__ dstS,
                                              float* __restrict__ eaS) {
  int e = blockIdx.x * TPB + threadIdx.x;
  if (e >= N_EDGES) return;
  int dst = ei[N_EDGES + e];
  int pos = atomicAdd(&cursor[dst], 1);
  srcS[pos] = ei[e];
  dstS[pos] = dst;
  eaS[pos] = ea[e];
}

// -------------------- input projection --------------------
__global__ __launch_bounds__(TPB) void k_lin_in(const float* __restrict__ x,
                                                const float* __restrict__ w,
                                                const float* __restrict__ b,
                                                float* __restrict__ h) {
  int i = blockIdx.x * TPB + threadIdx.x;
  if (i >= N_NODES) return;
  float xi[IN_DIM];
  const float4* xp = reinterpret_cast<const float4*>(x + i * IN_DIM);
#pragma unroll
  for (int q = 0; q < 4; ++q) {
    float4 v = xp[q];
    xi[4*q] = v.x; xi[4*q+1] = v.y; xi[4*q+2] = v.z; xi[4*q+3] = v.w;
  }
  float4* hp = reinterpret_cast<float4*>(h + i * HID);
#pragma unroll
  for (int j4 = 0; j4 < HID/4; ++j4) {
    float o[4];
#pragma unroll
    for (int c = 0; c < 4; ++c) {
      int j = j4*4 + c;
      float acc = b[j];
#pragma unroll
      for (int k = 0; k < IN_DIM; ++k) acc += xi[k] * w[k*HID + j];
      o[c] = acc;
    }
    float4 ov = {o[0], o[1], o[2], o[3]};
    hp[j4] = ov;
  }
}

// -------------------- per-node msg projections: P = h@W1[0:64]+b1, Q = h@W1[64:128] ----
__global__ __launch_bounds__(TPB) void k_pq(const float* __restrict__ h,
                                            const float* __restrict__ w1,
                                            const float* __restrict__ b1,
                                            float* __restrict__ P,
                                            float* __restrict__ Q) {
  int i = blockIdx.x * TPB + threadIdx.x;
  if (i >= N_NODES) return;
  float p[MLP_H], q[MLP_H];
#pragma unroll
  for (int j = 0; j < MLP_H; ++j) { p[j] = b1[j]; q[j] = 0.f; }
  const float4* hp = reinterpret_cast<const float4*>(h + i * HID);
#pragma unroll 2
  for (int k4 = 0; k4 < 16; ++k4) {
    float4 a = hp[k4];
    const float* wp = w1 + (k4*4) * MLP_H;
    const float* wq = w1 + (64 + k4*4) * MLP_H;
#pragma unroll
    for (int j = 0; j < MLP_H; ++j) {
      p[j] += a.x*wp[j] + a.y*wp[MLP_H+j] + a.z*wp[2*MLP_H+j] + a.w*wp[3*MLP_H+j];
      q[j] += a.x*wq[j] + a.y*wq[MLP_H+j] + a.z*wq[2*MLP_H+j] + a.w*wq[3*MLP_H+j];
    }
  }
  float4* pp = reinterpret_cast<float4*>(P + i * MLP_H);
  float4* qp = reinterpret_cast<float4*>(Q + i * MLP_H);
#pragma unroll
  for (int c = 0; c < MLP_H/4; ++c) {
    float4 pv = {p[4*c], p[4*c+1], p[4*c+2], p[4*c+3]};
    float4 qv = {q[4*c], q[4*c+1], q[4*c+2], q[4*c+3]};
    pp[c] = pv; qp[c] = qv;
  }
}

// -------------------- pass 1: gather + z compute + z1 store + BN1 stats ---------------
__global__ __launch_bounds__(TPB) void k_gather(const float* __restrict__ P,
                                                const float* __restrict__ Q,
                                                const int* __restrict__ srcS,
                                                const int* __restrict__ dstS,
                                                const float* __restrict__ eaS,
                                                const float* __restrict__ w1,
                                                float* __restrict__ z1,
                                                float* __restrict__ gstat) {
  const int lane = threadIdx.x & 63;
  const int k = lane & 31;
  const int half = lane >> 5;
  const float weak = w1[128 * MLP_H + k];
  float s = 0.f, q = 0.f;
  const int wv = blockIdx.x * 4 + (threadIdx.x >> 6);
  const int c0 = wv * PER_W;
  const int c1 = min(c0 + PER_W, N_EDGES);
  if (c0 < N_EDGES) {
    const int rounds = (c1 - c0 + 1) >> 1;
    const int e0 = c0 + half;
    int ec = min(e0, c1 - 1);
    bool vc = e0 < c1;
    float ac = eaS[ec];
    float qv = Q[srcS[ec] * MLP_H + k];
    float pv = P[dstS[ec] * MLP_H + k];
    for (int r = 0; r < rounds; ++r) {
      const int en = e0 + 2 * (r + 1);
      const int ecn = min(en, c1 - 1);
      const bool vn = en < c1;
      float an = eaS[ecn];
      float qn = Q[srcS[ecn] * MLP_H + k];
      float pn = P[dstS[ecn] * MLP_H + k];
      float z = pv + qv + ac * weak;
      if (vc) {
        z1[ec * MLP_H + k] = z;
        s += z; q = fmaf(z, z, q);
      }
      qv = qn; pv = pn; ac = an; vc = vn; ec = ecn;
    }
  }
  s += __shfl_xor(s, 32, 64);
  q += __shfl_xor(q, 32, 64);
  __shared__ float ls[4][MLP_H], lq[4][MLP_H];
  const int w = threadIdx.x >> 6;
  if (lane < MLP_H) { ls[w][lane] = s; lq[w][lane] = q; }
  __syncthreads();
  const int t = threadIdx.x;
  if (t < MLP_H)
    unsafeAtomicAdd(&gstat[t], ls[0][t] + ls[1][t] + ls[2][t] + ls[3][t]);
  else if (t < 2*MLP_H)
    unsafeAtomicAdd(&gstat[t], lq[0][t-MLP_H] + lq[1][t-MLP_H] + lq[2][t-MLP_H] + lq[3][t-MLP_H]);
}

// -------------------- pass 2: linear z1 -> m1 -> t (f16 dot2) -> aggregate + t-stats --
__global__ __launch_bounds__(TPB) void k_msgdot(const float* __restrict__ z1,
                                                const int* __restrict__ rs,
                                                const float* __restrict__ gstat_in, // BN1 stats
                                                const float* __restrict__ g1,
                                                const float* __restrict__ be1,
                                                const float* __restrict__ w2,
                                                const float* __restrict__ b2,
                                                float* __restrict__ agg,
                                                float* __restrict__ gstat_out) {
  const int lane = threadIdx.x & 63;
  const int k = lane & 31;
  const int half = lane >> 5;
  // inline BN1 coefficients for feature k
  const float mu1 = gstat_in[k] * (1.f / N_EDGES);
  const float var1 = fmaxf(gstat_in[MLP_H + k] * (1.f / N_EDGES) - mu1 * mu1, 0.f);
  const float a1k = g1[k] * rsqrtf(var1 + EPS);
  const float c1k = be1[k] - a1k * mu1;
  // packed f16 W2 columns: w2pk[i] = {w2[2i][lane], w2[2i+1][lane]}
  nh2 w2pk[16];
#pragma unroll
  for (int i = 0; i < 16; ++i)
    w2pk[i] = pack2(w2[(2*i) * HID + lane], w2[(2*i+1) * HID + lane]);
  const float b2j = b2[lane];
  const int wv = blockIdx.x * 4 + (threadIdx.x >> 6);
  const int key0 = min(wv * PER_W, N_EDGES);
  const int key1 = min((wv + 1) * PER_W, N_EDGES);
  const int n0 = lbound(rs, key0);
  const int n1 = (wv == NWAVES - 1) ? N_NODES : lbound(rs, key1);
  float sj = 0.f, qj = 0.f;
  for (int n = n0; n < n1; ++n) {
    const int start = rs[n], end = rs[n + 1];
    float aggj = 0.f;
    if (end > start) {
      const int rounds = (end - start + 1) >> 1;
      const int e0 = start + half;
      int ec = min(e0, end - 1);
      float zc = z1[ec * MLP_H + k];
      for (int r = 0; r < rounds; ++r) {
        const int en = min(e0 + 2 * (r + 1), end - 1);
        float zn = z1[en * MLP_H + k];                    // prefetch next (linear)
        const bool second = (start + 2 * r + 1) < end;    // wave-uniform
        float m = fmaxf(fmaf(a1k, zc, c1k), 0.f);
        float mn = __shfl_xor(m, 1, 64);                  // neighbor feature
        nh2 pk = pack2(m, mn);                            // lane 2i: {m[2i], m[2i+1]}
        float vA = b2j, vA2 = 0.f, vB = b2j, vB2 = 0.f;
#pragma unroll
        for (int i = 0; i < 16; i += 2) {
          vA  = dot2acc(bcast_h2(pk, 2*i),        w2pk[i],   vA);
          vA2 = dot2acc(bcast_h2(pk, 2*i + 2),    w2pk[i+1], vA2);
          vB  = dot2acc(bcast_h2(pk, 32 + 2*i),   w2pk[i],   vB);
          vB2 = dot2acc(bcast_h2(pk, 32 + 2*i+2), w2pk[i+1], vB2);
        }
        float v0 = fmaxf(vA + vA2, 0.f);
        aggj += v0; sj += v0; qj = fmaf(v0, v0, qj);
        if (second) {
          float v1 = fmaxf(vB + vB2, 0.f);
          aggj += v1; sj += v1; qj = fmaf(v1, v1, qj);
        }
        zc = zn;
      }
    }
    agg[n * HID + lane] = aggj;
  }
  __shared__ float ls[4][HID], lq[4][HID];
  const int w = threadIdx.x >> 6;
  ls[w][lane] = sj; lq[w][lane] = qj;
  __syncthreads();
  const int t = threadIdx.x;
  if (t < HID)
    unsafeAtomicAdd(&gstat_out[t], ls[0][t] + ls[1][t] + ls[2][t] + ls[3][t]);
  else if (t < 2*HID)
    unsafeAtomicAdd(&gstat_out[t], lq[0][t-HID] + lq[1][t-HID] + lq[2][t-HID] + lq[3][t-HID]);
}

// -------------------- update stage 1 + zu1 stats (BN2 coefs inline via LDS) -----------
__global__ __launch_bounds__(TPB) void k_upd1(const float* __restrict__ h,
                                              const float* __restrict__ agg,
                                              const int* __restrict__ deg,
                                              const float* __restrict__ gstat_in, // t stats (E count)
                                              const float* __restrict__ g2,
                                              const float* __restrict__ be2,
                                              const float* __restrict__ w1,
                                              const float* __restrict__ b1,
                                              float* __restrict__ zu1,
                                              float* __restrict__ gstat_out) {
  __shared__ float sa[HID], sc[HID];
  {
    int t = threadIdx.x;
    if (t < HID) {
      float mu = gstat_in[t] * (1.f / N_EDGES);
      float var = fmaxf(gstat_in[HID + t] * (1.f / N_EDGES) - mu * mu, 0.f);
      float a = g2[t] * rsqrtf(var + EPS);
      sa[t] = a; sc[t] = be2[t] - a * mu;
    }
  }
  __syncthreads();
  int i = blockIdx.x * TPB + threadIdx.x;
  bool valid = i < N_NODES;
  float acc[MLP_H];
#pragma unroll
  for (int j = 0; j < MLP_H; ++j) acc[j] = 0.f;
  if (valid) {
#pragma unroll
    for (int j = 0; j < MLP_H; ++j) acc[j] = b1[j];
    const float4* hp = reinterpret_cast<const float4*>(h + i * HID);
#pragma unroll 2
    for (int k4 = 0; k4 < 16; ++k4) {
      float4 a = hp[k4];
      const float* wr = w1 + (k4*4) * MLP_H;
#pragma unroll
      for (int j = 0; j < MLP_H; ++j)
        acc[j] += a.x*wr[j] + a.y*wr[MLP_H+j] + a.z*wr[2*MLP_H+j] + a.w*wr[3*MLP_H+j];
    }
    float degf = (float)deg[i];
    const float4* ap = reinterpret_cast<const float4*>(agg + i * HID);
#pragma unroll 2
    for (int k4 = 0; k4 < 16; ++k4) {
      float4 g4 = ap[k4];
      int k = k4*4;
      float a0 = sa[k]  *g4.x + sc[k]  *degf;
      float a1 = sa[k+1]*g4.y + sc[k+1]*degf;
      float a2 = sa[k+2]*g4.z + sc[k+2]*degf;
      float a3 = sa[k+3]*g4.w + sc[k+3]*degf;
      const float* wr = w1 + (64 + k) * MLP_H;
#pragma unroll
      for (int j = 0; j < MLP_H; ++j)
        acc[j] += a0*wr[j] + a1*wr[MLP_H+j] + a2*wr[2*MLP_H+j] + a3*wr[3*MLP_H+j];
    }
    float4* zp = reinterpret_cast<float4*>(zu1 + i * MLP_H);
#pragma unroll
    for (int c = 0; c < MLP_H/4; ++c) {
      float4 o = {acc[4*c], acc[4*c+1], acc[4*c+2], acc[4*c+3]};
      zp[c] = o;
    }
  }
  int lane = threadIdx.x & 63;
  float ks = 0.f, kq = 0.f;
#pragma unroll
  for (int j = 0; j < MLP_H; ++j) {
    float sv = wsum(acc[j]);
    float qv = wsum(acc[j]*acc[j]);
    if (lane == j) { ks = sv; kq = qv; }
  }
  __shared__ float ls[4][MLP_H], lq[4][MLP_H];
  int w = threadIdx.x >> 6;
  if (lane < MLP_H) { ls[w][lane] = ks; lq[w][lane] = kq; }
  __syncthreads();
  int t = threadIdx.x;
  if (t < MLP_H)
    unsafeAtomicAdd(&gstat_out[t], ls[0][t] + ls[1][t] + ls[2][t] + ls[3][t]);
  else if (t < 2*MLP_H)
    unsafeAtomicAdd(&gstat_out[t], lq[0][t-MLP_H] + lq[1][t-MLP_H] + lq[2][t-MLP_H] + lq[3][t-MLP_H]);
}

// -------------------- update stage 2 + tu stats (BNu1 coefs inline via LDS) -----------
__global__ __launch_bounds__(TPB) void k_upd2(const float* __restrict__ zu1,
                                              const float* __restrict__ gstat_in, // zu1 stats (N count)
                                              const float* __restrict__ gu1,
                                              const float* __restrict__ beu1,
                                              const float* __restrict__ w2,
                                              const float* __restrict__ b2,
                                              float* __restrict__ tu,
                                              float* __restrict__ gstat_out) {
  __shared__ float sa[MLP_H], sc[MLP_H];
  {
    int t = threadIdx.x;
    if (t < MLP_H) {
      float mu = gstat_in[t] * (1.f / N_NODES);
      float var = fmaxf(gstat_in[MLP_H + t] * (1.f / N_NODES) - mu * mu, 0.f);
      float a = gu1[t] * rsqrtf(var + EPS);
      sa[t] = a; sc[t] = beu1[t] - a * mu;
    }
  }
  __syncthreads();
  int i = blockIdx.x * TPB + threadIdx.x;
  bool valid = i < N_NODES;
  float m1[MLP_H];
#pragma unroll
  for (int kk = 0; kk < MLP_H; ++kk) m1[kk] = 0.f;
  if (valid) {
    const float4* zp = reinterpret_cast<const float4*>(zu1 + i * MLP_H);
#pragma unroll
    for (int c = 0; c < MLP_H/4; ++c) {
      float4 z = zp[c];
      int kk = 4*c;
      m1[kk]   = fmaxf(sa[kk]  *z.x + sc[kk],   0.f);
      m1[kk+1] = fmaxf(sa[kk+1]*z.y + sc[kk+1], 0.f);
      m1[kk+2] = fmaxf(sa[kk+2]*z.z + sc[kk+2], 0.f);
      m1[kk+3] = fmaxf(sa[kk+3]*z.w + sc[kk+3], 0.f);
    }
  }
  int lane = threadIdx.x & 63;
  float ks = 0.f, kq = 0.f;
#pragma unroll 2
  for (int j4 = 0; j4 < HID/4; ++j4) {
    float tv[4];
#pragma unroll
    for (int c = 0; c < 4; ++c) {
      int j = j4*4 + c;
      float v = 0.f;
      if (valid) {
        v = b2[j];
#pragma unroll
        for (int kk = 0; kk < MLP_H; ++kk) v += m1[kk] * w2[kk*HID + j];
        v = fmaxf(v, 0.f);
      }
      tv[c] = v;
      float sv = wsum(v);
      float qv = wsum(v*v);
      if (lane == j) { ks = sv; kq = qv; }
    }
    if (valid) {
      float4 o = {tv[0], tv[1], tv[2], tv[3]};
      *reinterpret_cast<float4*>(tu + i * HID + j4*4) = o;
    }
  }
  __shared__ float ls[4][HID], lq[4][HID];
  int w = threadIdx.x >> 6;
  ls[w][lane] = ks; lq[w][lane] = kq;
  __syncthreads();
  int t = threadIdx.x;
  if (t < HID)
    unsafeAtomicAdd(&gstat_out[t], ls[0][t] + ls[1][t] + ls[2][t] + ls[3][t]);
  else if (t < 2*HID)
    unsafeAtomicAdd(&gstat_out[t], lq[0][t-HID] + lq[1][t-HID] + lq[2][t-HID] + lq[3][t-HID]);
}

// -------------------- residual (BNu2 coefs inline via LDS) --------------------
__global__ __launch_bounds__(TPB) void k_resid(float* __restrict__ h,
                                               const float* __restrict__ tu,
                                               const float* __restrict__ gstat_in, // tu stats (N count)
                                               const float* __restrict__ gu2,
                                               const float* __restrict__ beu2) {
  __shared__ float sa[HID], sc[HID];
  {
    int t = threadIdx.x;
    if (t < HID) {
      float mu = gstat_in[t] * (1.f / N_NODES);
      float var = fmaxf(gstat_in[HID + t] * (1.f / N_NODES) - mu * mu, 0.f);
      float a = gu2[t] * rsqrtf(var + EPS);
      sa[t] = a; sc[t] = beu2[t] - a * mu;
    }
  }
  __syncthreads();
  int idx = blockIdx.x * TPB + threadIdx.x;
  if (idx >= N_NODES * (HID/4)) return;
  int j0 = (idx & (HID/4 - 1)) * 4;
  float4 hv = reinterpret_cast<const float4*>(h)[idx];
  float4 tv = reinterpret_cast<const float4*>(tu)[idx];
  hv.x += sa[j0]  *tv.x + sc[j0];
  hv.y += sa[j0+1]*tv.y + sc[j0+1];
  hv.z += sa[j0+2]*tv.z + sc[j0+2];
  hv.w += sa[j0+3]*tv.w + sc[j0+3];
  reinterpret_cast<float4*>(h)[idx] = hv;
}

// -------------------- pool + head --------------------
__global__ __launch_bounds__(TPB) void k_pool_head(const float* __restrict__ h,
                                                   const int* __restrict__ batch,
                                                   const float* __restrict__ ow,
                                                   const float* __restrict__ ob,
                                                   float* __restrict__ out) {
  int g = blockIdx.x;
  int lo = 0, hi = N_NODES;
  while (lo < hi) { int mid = (lo+hi) >> 1; if (batch[mid] < g) lo = mid+1; else hi = mid; }
  int start = lo;
  lo = start; hi = N_NODES;
  while (lo < hi) { int mid = (lo+hi) >> 1; if (batch[mid] < g+1) lo = mid+1; else hi = mid; }
  int end = lo;
  int j = threadIdx.x & 63;
  int sub = threadIdx.x >> 6;
  float acc = 0.f;
  for (int n = start + sub; n < end; n += 4) acc += h[n*HID + j];
  __shared__ float red[TPB];
  red[threadIdx.x] = acc;
  __syncthreads();
  if (threadIdx.x < 64) {
    float s = red[threadIdx.x] + red[64+threadIdx.x] + red[128+threadIdx.x] + red[192+threadIdx.x];
    float cnt = (float)(end - start);
    float pooled = s / fmaxf(cnt, 1.0f);
    float v = pooled * ow[threadIdx.x];
    v = wsum(v);
    if (threadIdx.x == 0) out[g] = fmaxf(v + ob[0], 0.f);
  }
}

// -------------------- launch --------------------
extern "C" void kernel_launch(void* const* d_in, const int* in_sizes, int n_in,
                              void* d_out, int out_size, void* d_ws, size_t ws_size,
                              hipStream_t stream) {
  const float* x       = (const float*)d_in[0];
  const int*   ei      = (const int*)  d_in[1];
  const float* ea      = (const float*)d_in[2];
  const int*   batch   = (const int*)  d_in[3];
  const float* lin_w   = (const float*)d_in[4];
  const float* lin_b   = (const float*)d_in[5];
  const float* msg_w1  = (const float*)d_in[6];
  const float* msg_b1  = (const float*)d_in[7];
  const float* msg_g1  = (const float*)d_in[8];
  const float* msg_be1 = (const float*)d_in[9];
  const float* msg_w2  = (const float*)d_in[10];
  const float* msg_b2  = (const float*)d_in[11];
  const float* msg_g2  = (const float*)d_in[12];
  const float* msg_be2 = (const float*)d_in[13];
  const float* upd_w1  = (const float*)d_in[14];
  const float* upd_b1  = (const float*)d_in[15];
  const float* upd_g1  = (const float*)d_in[16];
  const float* upd_be1 = (const float*)d_in[17];
  const float* upd_w2  = (const float*)d_in[18];
  const float* upd_b2  = (const float*)d_in[19];
  const float* upd_g2  = (const float*)d_in[20];
  const float* upd_be2 = (const float*)d_in[21];
  const float* out_w   = (const float*)d_in[22];
  const float* out_b   = (const float*)d_in[23];
  float* out = (float*)d_out;

  float* W     = (float*)d_ws;
  float* h     = W;                       //  6,400,000
  float* P     = W + 6400000;             //  3,200,000
  float* Qb    = W + 9600000;             //  3,200,000
  float* agg   = W + 12800000;            //  6,400,000
  float* z1    = W + 19200000;            // 25,600,000
  float* zu1   = z1;                      //  (alias: z1 dead when written)
  float* tu    = z1 + 3200000;            //  (alias)
  float* eaS   = W + 44800000;            //    800,000
  float* stats = W + 45600000;            //  3*384
  int*   ib    = (int*)(W + 45601152);
  int* deg       = ib;                    //   100,000
  int* row_start = ib + 100000;           //   100,001
  int* cursor    = ib + 200001;           //   100,000
  int* srcS      = ib + 300001;           //   800,000
  int* dstS      = ib + 1100001;          //   800,000
  int* partials  = ib + 1900001;          //   NCHUNK

  hipMemsetAsync(stats, 0, 3*384*sizeof(float), stream);
  hipMemsetAsync(deg, 0, N_NODES*sizeof(int), stream);

  // CSR build
  k_deg<<<N_EDGES/TPB, TPB, 0, stream>>>(ei, deg);
  k_scan_part<<<NCHUNK, SCAN_B, 0, stream>>>(deg, partials);
  k_scan_mid<<<1, 1, 0, stream>>>(partials, row_start);
  k_scan_fin<<<NCHUNK, SCAN_B, 0, stream>>>(deg, partials, row_start, cursor);
  k_fill<<<N_EDGES/TPB, TPB, 0, stream>>>(ei, ea, cursor, srcS, dstS, eaS);

  k_lin_in<<<(N_NODES+TPB-1)/TPB, TPB, 0, stream>>>(x, lin_w, lin_b, h);

  const int NODE_BLKS = (N_NODES + TPB - 1) / TPB;       // 391

  for (int l = 0; l < 3; ++l) {
    const float* mw1 = msg_w1 + (size_t)l*129*MLP_H;
    const float* mb1 = msg_b1 + l*MLP_H;
    const float* mg1 = msg_g1 + l*MLP_H;
    const float* mbe1= msg_be1 + l*MLP_H;
    const float* mw2 = msg_w2 + (size_t)l*MLP_H*HID;
    const float* mb2 = msg_b2 + l*HID;
    const float* mg2 = msg_g2 + l*HID;
    const float* mbe2= msg_be2 + l*HID;
    const float* uw1 = upd_w1 + (size_t)l*128*MLP_H;
    const float* ub1 = upd_b1 + l*MLP_H;
    const float* ug1 = upd_g1 + l*MLP_H;
    const float* ube1= upd_be1 + l*MLP_H;
    const float* uw2 = upd_w2 + (size_t)l*MLP_H*HID;
    const float* ub2 = upd_b2 + l*HID;
    const float* ug2 = upd_g2 + l*HID;
    const float* ube2= upd_be2 + l*HID;
    float* st = stats + l*384;   // [0:64) BN1 | [64:192) BN2 | [192:256) BNu1 | [256:384) BNu2

    k_pq<<<NODE_BLKS, TPB, 0, stream>>>(h, mw1, mb1, P, Qb);
    k_gather<<<GSB, TPB, 0, stream>>>(P, Qb, srcS, dstS, eaS, mw1, z1, st);
    k_msgdot<<<GSB, TPB, 0, stream>>>(z1, row_start, st, mg1, mbe1, mw2, mb2, agg, st+64);
    k_upd1<<<NODE_BLKS, TPB, 0, stream>>>(h, agg, deg, st+64, mg2, mbe2, uw1, ub1, zu1, st+192);
    k_upd2<<<NODE_BLKS, TPB, 0, stream>>>(zu1, st+192, ug1, ube1, uw2, ub2, tu, st+256);
    k_resid<<<(N_NODES*(HID/4)+TPB-1)/TPB, TPB, 0, stream>>>(h, tu, st+256, ug2, ube2);
  }

  k_pool_head<<<NUM_GRAPHS, TPB, 0, stream>>>(h, batch, out_w, out_b, out);
}

// Round 6
// 1137.867 us; speedup vs baseline: 7.7782x; 1.0573x over previous
//
#include <hip/hip_runtime.h>
#include <hip/hip_bf16.h>

#define N_NODES   100000
#define N_EDGES   800000
#define NUM_GRAPHS 512
#define IN_DIM    16
#define HID       64
#define MLP_H     32
#define EPS       1e-5f
#define TPB       256
#define SCAN_B    1024
#define NCHUNK    ((N_NODES + SCAN_B - 1) / SCAN_B)   // 98
#define GSB       2048
#define NWAVES    (GSB * 4)                           // 8192
#define PER_W     ((N_EDGES + NWAVES - 1) / NWAVES)   // 98 edges per wave

using nh2   = decltype(__builtin_amdgcn_cvt_pkrtz(0.f, 0.f));  // packed 2x f16
typedef _Float16 f16x8 __attribute__((ext_vector_type(8)));
typedef float    f32x4 __attribute__((ext_vector_type(4)));
typedef int      i32x4 __attribute__((ext_vector_type(4)));

__device__ __forceinline__ nh2 pack2(float a, float b) {
  return __builtin_amdgcn_cvt_pkrtz(a, b);
}
__device__ __forceinline__ float wsum(float v) {
  v += __shfl_xor(v, 1, 64);
  v += __shfl_xor(v, 2, 64);
  v += __shfl_xor(v, 4, 64);
  v += __shfl_xor(v, 8, 64);
  v += __shfl_xor(v, 16, 64);
  v += __shfl_xor(v, 32, 64);
  return v;
}
__device__ __forceinline__ int lbound(const int* __restrict__ rs, int key) {
  int lo = 0, hi = N_NODES;
  while (lo < hi) { int m = (lo + hi) >> 1; if (rs[m] < key) lo = m + 1; else hi = m; }
  return lo;
}

// -------------------- CSR build --------------------
__global__ __launch_bounds__(TPB) void k_deg(const int* __restrict__ ei, int* __restrict__ deg) {
  int e = blockIdx.x * TPB + threadIdx.x;
  if (e < N_EDGES) atomicAdd(&deg[ei[N_EDGES + e]], 1);
}

__global__ __launch_bounds__(SCAN_B) void k_scan_part(const int* __restrict__ deg,
                                                      int* __restrict__ partials) {
  __shared__ int red[SCAN_B];
  int i = blockIdx.x * SCAN_B + threadIdx.x;
  red[threadIdx.x] = (i < N_NODES) ? deg[i] : 0;
  __syncthreads();
  for (int off = SCAN_B / 2; off > 0; off >>= 1) {
    if (threadIdx.x < off) red[threadIdx.x] += red[threadIdx.x + off];
    __syncthreads();
  }
  if (threadIdx.x == 0) partials[blockIdx.x] = red[0];
}

__global__ void k_scan_mid(int* __restrict__ partials, int* __restrict__ row_start) {
  int run = 0;
  for (int b = 0; b < NCHUNK; ++b) { int t = partials[b]; partials[b] = run; run += t; }
  row_start[N_NODES] = run;  // == N_EDGES
}

__global__ __launch_bounds__(SCAN_B) void k_scan_fin(const int* __restrict__ deg,
                                                     const int* __restrict__ partials,
                                                     int* __restrict__ row_start,
                                                     int* __restrict__ cursor) {
  __shared__ int buf[2][SCAN_B];
  int t = threadIdx.x, i = blockIdx.x * SCAN_B + t;
  int v = (i < N_NODES) ? deg[i] : 0;
  buf[0][t] = v;
  __syncthreads();
  int cur = 0;
  for (int off = 1; off < SCAN_B; off <<= 1) {
    int nv = buf[cur][t] + ((t >= off) ? buf[cur][t - off] : 0);
    buf[cur ^ 1][t] = nv; cur ^= 1;
    __syncthreads();
  }
  if (i < N_NODES) {
    int excl = buf[cur][t] - v + partials[blockIdx.x];
    row_start[i] = excl;
    cursor[i] = excl;
  }
}

__global__ __launch_bounds__(TPB) void k_fill(const int* __restrict__ ei,
                                              const float* __restrict__ ea,
                                              int* __restrict__ cursor,
                                              int* __restrict__ srcS,
                                              int* __restrict__ dstS,
                                              float* __restrict__ eaS) {
  int e = blockIdx.x * TPB + threadIdx.x;
  if (e >= N_EDGES) return;
  int dst = ei[N_EDGES + e];
  int pos = atomicAdd(&cursor[dst], 1);
  srcS[pos] = ei[e];
  dstS[pos] = dst;
  eaS[pos] = ea[e];
}

// -------------------- input projection --------------------
__global__ __launch_bounds__(TPB) void k_lin_in(const float* __restrict__ x,
                                                const float* __restrict__ w,
                                                const float* __restrict__ b,
                                                float* __restrict__ h) {
  int i = blockIdx.x * TPB + threadIdx.x;
  if (i >= N_NODES) return;
  float xi[IN_DIM];
  const float4* xp = reinterpret_cast<const float4*>(x + i * IN_DIM);
#pragma unroll
  for (int q = 0; q < 4; ++q) {
    float4 v = xp[q];
    xi[4*q] = v.x; xi[4*q+1] = v.y; xi[4*q+2] = v.z; xi[4*q+3] = v.w;
  }
  float4* hp = reinterpret_cast<float4*>(h + i * HID);
#pragma unroll
  for (int j4 = 0; j4 < HID/4; ++j4) {
    float o[4];
#pragma unroll
    for (int c = 0; c < 4; ++c) {
      int j = j4*4 + c;
      float acc = b[j];
#pragma unroll
      for (int k = 0; k < IN_DIM; ++k) acc += xi[k] * w[k*HID + j];
      o[c] = acc;
    }
    float4 ov = {o[0], o[1], o[2], o[3]};
    hp[j4] = ov;
  }
}

// -------------------- per-node msg projections: P = h@W1[0:64]+b1, Q = h@W1[64:128] ----
__global__ __launch_bounds__(TPB) void k_pq(const float* __restrict__ h,
                                            const float* __restrict__ w1,
                                            const float* __restrict__ b1,
                                            float* __restrict__ P,
                                            float* __restrict__ Q) {
  int i = blockIdx.x * TPB + threadIdx.x;
  if (i >= N_NODES) return;
  float p[MLP_H], q[MLP_H];
#pragma unroll
  for (int j = 0; j < MLP_H; ++j) { p[j] = b1[j]; q[j] = 0.f; }
  const float4* hp = reinterpret_cast<const float4*>(h + i * HID);
#pragma unroll 2
  for (int k4 = 0; k4 < 16; ++k4) {
    float4 a = hp[k4];
    const float* wp = w1 + (k4*4) * MLP_H;
    const float* wq = w1 + (64 + k4*4) * MLP_H;
#pragma unroll
    for (int j = 0; j < MLP_H; ++j) {
      p[j] += a.x*wp[j] + a.y*wp[MLP_H+j] + a.z*wp[2*MLP_H+j] + a.w*wp[3*MLP_H+j];
      q[j] += a.x*wq[j] + a.y*wq[MLP_H+j] + a.z*wq[2*MLP_H+j] + a.w*wq[3*MLP_H+j];
    }
  }
  float4* pp = reinterpret_cast<float4*>(P + i * MLP_H);
  float4* qp = reinterpret_cast<float4*>(Q + i * MLP_H);
#pragma unroll
  for (int c = 0; c < MLP_H/4; ++c) {
    float4 pv = {p[4*c], p[4*c+1], p[4*c+2], p[4*c+3]};
    float4 qv = {q[4*c], q[4*c+1], q[4*c+2], q[4*c+3]};
    pp[c] = pv; qp[c] = qv;
  }
}

// -------------------- pass 1: gather + z compute + z1(f16) store + BN1 stats ----------
// depth-2 software pipeline on the random gathers
__global__ __launch_bounds__(TPB) void k_gather(const float* __restrict__ P,
                                                const float* __restrict__ Q,
                                                const int* __restrict__ srcS,
                                                const int* __restrict__ dstS,
                                                const float* __restrict__ eaS,
                                                const float* __restrict__ w1,
                                                _Float16* __restrict__ z1h,
                                                float* __restrict__ gstat) {
  const int lane = threadIdx.x & 63;
  const int k = lane & 31;
  const int half = lane >> 5;
  const float weak = w1[128 * MLP_H + k];
  float s = 0.f, q = 0.f;
  const int wv = blockIdx.x * 4 + (threadIdx.x >> 6);
  const int c0 = wv * PER_W;
  const int c1 = min(c0 + PER_W, N_EDGES);
  if (c0 < N_EDGES) {
    const int rounds = (c1 - c0 + 1) >> 1;
    const int e0 = c0 + half;
    int ea0 = min(e0, c1 - 1);
    int ea1 = min(e0 + 2, c1 - 1);
    float aA = eaS[ea0], aB = eaS[ea1];
    float qA = Q[srcS[ea0] * MLP_H + k], qB = Q[srcS[ea1] * MLP_H + k];
    float pA = P[dstS[ea0] * MLP_H + k], pB = P[dstS[ea1] * MLP_H + k];
    for (int r = 0; r < rounds; ++r) {
      const int ecur = e0 + 2 * r;
      const bool vc = ecur < c1;
      const int ecl = min(ecur, c1 - 1);
      float z = pA + qA + aA * weak;
      pA = pB; qA = qB; aA = aB;
      const int en = min(e0 + 2 * (r + 2), c1 - 1);
      aB = eaS[en]; qB = Q[srcS[en] * MLP_H + k]; pB = P[dstS[en] * MLP_H + k];
      if (vc) {
        z1h[ecl * MLP_H + k] = (_Float16)z;
        s += z; q = fmaf(z, z, q);
      }
    }
  }
  s += __shfl_xor(s, 32, 64);
  q += __shfl_xor(q, 32, 64);
  __shared__ float ls[4][MLP_H], lq[4][MLP_H];
  const int w = threadIdx.x >> 6;
  if (lane < MLP_H) { ls[w][lane] = s; lq[w][lane] = q; }
  __syncthreads();
  const int t = threadIdx.x;
  if (t < MLP_H)
    unsafeAtomicAdd(&gstat[t], ls[0][t] + ls[1][t] + ls[2][t] + ls[3][t]);
  else if (t < 2*MLP_H)
    unsafeAtomicAdd(&gstat[t], lq[0][t-MLP_H] + lq[1][t-MLP_H] + lq[2][t-MLP_H] + lq[3][t-MLP_H]);
}

// -------------------- pass 2: MFMA msg2 + aggregate + t-stats --------------------
// Per 16-edge tile: A = m1 (16x32 f16, row=lane&15, k=(lane>>4)*8+i),
// B = W2 f16 (k same mapping, col=lane&15), C f32 (row=(lane>>4)*4+reg edges,
// col=lane&15 features). 4 MFMAs cover the 64 output features.
__global__ __launch_bounds__(TPB) void k_msgdot(const _Float16* __restrict__ z1h,
                                                const int* __restrict__ rs,
                                                const float* __restrict__ gstat_in, // BN1 stats
                                                const float* __restrict__ g1,
                                                const float* __restrict__ be1,
                                                const float* __restrict__ w2,
                                                const float* __restrict__ b2,
                                                float* __restrict__ agg,
                                                float* __restrict__ gstat_out) {
  const int lane = threadIdx.x & 63;
  const int col = lane & 15;
  const int g   = lane >> 4;
  // BN1 coefs for this lane's 8 K-features kf = g*8+i
  float a1v[8], c1v[8];
#pragma unroll
  for (int i = 0; i < 8; ++i) {
    int kf = g*8 + i;
    float mu = gstat_in[kf] * (1.f / N_EDGES);
    float var = fmaxf(gstat_in[MLP_H + kf] * (1.f / N_EDGES) - mu * mu, 0.f);
    float a = g1[kf] * rsqrtf(var + EPS);
    a1v[i] = a; c1v[i] = be1[kf] - a * mu;
  }
  // B fragments: 4 chunks of 16 output features
  f16x8 bf0, bf1, bf2, bf3;
#define MKB(BF, C) { i32x4 bw; \
  _Pragma("unroll") for (int ii = 0; ii < 4; ++ii) { \
    nh2 p = pack2(w2[(g*8 + 2*ii) * HID + (C)*16 + col], \
                  w2[(g*8 + 2*ii + 1) * HID + (C)*16 + col]); \
    bw[ii] = __builtin_bit_cast(int, p); } \
  BF = __builtin_bit_cast(f16x8, bw); }
  MKB(bf0, 0) MKB(bf1, 1) MKB(bf2, 2) MKB(bf3, 3)
#undef MKB
  float b2c[4];
#pragma unroll
  for (int c = 0; c < 4; ++c) b2c[c] = b2[c*16 + col];

  float sacc[4] = {0.f,0.f,0.f,0.f}, qacc[4] = {0.f,0.f,0.f,0.f};
  const int wv = blockIdx.x * 4 + (threadIdx.x >> 6);
  const int key0 = min(wv * PER_W, N_EDGES);
  const int key1 = min((wv + 1) * PER_W, N_EDGES);
  const int n0 = lbound(rs, key0);
  const int n1 = (wv == NWAVES - 1) ? N_NODES : lbound(rs, key1);

  for (int n = n0; n < n1; ++n) {
    const int start = rs[n], end = rs[n + 1];
    float aggacc[4] = {0.f,0.f,0.f,0.f};
    for (int t0 = start; t0 < end; t0 += 16) {
      const int ec = min(t0 + col, end - 1);
      f16x8 zv = *reinterpret_cast<const f16x8*>(z1h + ec * MLP_H + g * 8);
      // m1 = relu(a1*z + c1), repacked to f16
      i32x4 aw;
#pragma unroll
      for (int i = 0; i < 4; ++i) {
        float m0 = fmaxf(fmaf(a1v[2*i],   (float)zv[2*i],   c1v[2*i]),   0.f);
        float m1 = fmaxf(fmaf(a1v[2*i+1], (float)zv[2*i+1], c1v[2*i+1]), 0.f);
        aw[i] = __builtin_bit_cast(int, pack2(m0, m1));
      }
      f16x8 af = __builtin_bit_cast(f16x8, aw);
      f32x4 zc = {0.f,0.f,0.f,0.f};
      f32x4 cc0 = __builtin_amdgcn_mfma_f32_16x16x32_f16(af, bf0, zc, 0, 0, 0);
      f32x4 cc1 = __builtin_amdgcn_mfma_f32_16x16x32_f16(af, bf1, zc, 0, 0, 0);
      f32x4 cc2 = __builtin_amdgcn_mfma_f32_16x16x32_f16(af, bf2, zc, 0, 0, 0);
      f32x4 cc3 = __builtin_amdgcn_mfma_f32_16x16x32_f16(af, bf3, zc, 0, 0, 0);
      bool vld[4];
#pragma unroll
      for (int reg = 0; reg < 4; ++reg) vld[reg] = (t0 + g*4 + reg) < end;
#define EPI(CC, CI) { \
  _Pragma("unroll") for (int reg = 0; reg < 4; ++reg) { \
    float tv = fmaxf(CC[reg] + b2c[CI], 0.f); \
    tv = vld[reg] ? tv : 0.f; \
    aggacc[CI] += tv; qacc[CI] = fmaf(tv, tv, qacc[CI]); } }
      EPI(cc0, 0) EPI(cc1, 1) EPI(cc2, 2) EPI(cc3, 3)
#undef EPI
    }
#pragma unroll
    for (int c = 0; c < 4; ++c) sacc[c] += aggacc[c];
    // combine the 4 row-groups -> full per-feature node sums
#pragma unroll
    for (int c = 0; c < 4; ++c) {
      aggacc[c] += __shfl_xor(aggacc[c], 16, 64);
      aggacc[c] += __shfl_xor(aggacc[c], 32, 64);
    }
    float aout = (g == 0) ? aggacc[0] : (g == 1) ? aggacc[1] : (g == 2) ? aggacc[2] : aggacc[3];
    agg[n * HID + g * 16 + col] = aout;
  }
  // stats: combine row-groups, then block LDS combine + atomic flush
#pragma unroll
  for (int c = 0; c < 4; ++c) {
    sacc[c] += __shfl_xor(sacc[c], 16, 64);
    sacc[c] += __shfl_xor(sacc[c], 32, 64);
    qacc[c] += __shfl_xor(qacc[c], 16, 64);
    qacc[c] += __shfl_xor(qacc[c], 32, 64);
  }
  __shared__ float ls[4][HID], lq[4][HID];
  const int w = threadIdx.x >> 6;
  if (g == 0) {
#pragma unroll
    for (int c = 0; c < 4; ++c) { ls[w][c*16 + col] = sacc[c]; lq[w][c*16 + col] = qacc[c]; }
  }
  __syncthreads();
  const int t = threadIdx.x;
  if (t < HID)
    unsafeAtomicAdd(&gstat_out[t], ls[0][t] + ls[1][t] + ls[2][t] + ls[3][t]);
  else if (t < 2*HID)
    unsafeAtomicAdd(&gstat_out[t], lq[0][t-HID] + lq[1][t-HID] + lq[2][t-HID] + lq[3][t-HID]);
}

// -------------------- update stage 1 + zu1 stats (BN2 coefs inline via LDS) -----------
__global__ __launch_bounds__(TPB) void k_upd1(const float* __restrict__ h,
                                              const float* __restrict__ agg,
                                              const int* __restrict__ deg,
                                              const float* __restrict__ gstat_in, // t stats (E count)
                                              const float* __restrict__ g2,
                                              const float* __restrict__ be2,
                                              const float* __restrict__ w1,
                                              const float* __restrict__ b1,
                                              float* __restrict__ zu1,
                                              float* __restrict__ gstat_out) {
  __shared__ float sa[HID], sc[HID];
  {
    int t = threadIdx.x;
    if (t < HID) {
      float mu = gstat_in[t] * (1.f / N_EDGES);
      float var = fmaxf(gstat_in[HID + t] * (1.f / N_EDGES) - mu * mu, 0.f);
      float a = g2[t] * rsqrtf(var + EPS);
      sa[t] = a; sc[t] = be2[t] - a * mu;
    }
  }
  __syncthreads();
  int i = blockIdx.x * TPB + threadIdx.x;
  bool valid = i < N_NODES;
  float acc[MLP_H];
#pragma unroll
  for (int j = 0; j < MLP_H; ++j) acc[j] = 0.f;
  if (valid) {
#pragma unroll
    for (int j = 0; j < MLP_H; ++j) acc[j] = b1[j];
    const float4* hp = reinterpret_cast<const float4*>(h + i * HID);
#pragma unroll 2
    for (int k4 = 0; k4 < 16; ++k4) {
      float4 a = hp[k4];
      const float* wr = w1 + (k4*4) * MLP_H;
#pragma unroll
      for (int j = 0; j < MLP_H; ++j)
        acc[j] += a.x*wr[j] + a.y*wr[MLP_H+j] + a.z*wr[2*MLP_H+j] + a.w*wr[3*MLP_H+j];
    }
    float degf = (float)deg[i];
    const float4* ap = reinterpret_cast<const float4*>(agg + i * HID);
#pragma unroll 2
    for (int k4 = 0; k4 < 16; ++k4) {
      float4 g4 = ap[k4];
      int k = k4*4;
      float a0 = sa[k]  *g4.x + sc[k]  *degf;
      float a1 = sa[k+1]*g4.y + sc[k+1]*degf;
      float a2 = sa[k+2]*g4.z + sc[k+2]*degf;
      float a3 = sa[k+3]*g4.w + sc[k+3]*degf;
      const float* wr = w1 + (64 + k) * MLP_H;
#pragma unroll
      for (int j = 0; j < MLP_H; ++j)
        acc[j] += a0*wr[j] + a1*wr[MLP_H+j] + a2*wr[2*MLP_H+j] + a3*wr[3*MLP_H+j];
    }
    float4* zp = reinterpret_cast<float4*>(zu1 + i * MLP_H);
#pragma unroll
    for (int c = 0; c < MLP_H/4; ++c) {
      float4 o = {acc[4*c], acc[4*c+1], acc[4*c+2], acc[4*c+3]};
      zp[c] = o;
    }
  }
  int lane = threadIdx.x & 63;
  float ks = 0.f, kq = 0.f;
#pragma unroll
  for (int j = 0; j < MLP_H; ++j) {
    float sv = wsum(acc[j]);
    float qv = wsum(acc[j]*acc[j]);
    if (lane == j) { ks = sv; kq = qv; }
  }
  __shared__ float ls[4][MLP_H], lq[4][MLP_H];
  int w = threadIdx.x >> 6;
  if (lane < MLP_H) { ls[w][lane] = ks; lq[w][lane] = kq; }
  __syncthreads();
  int t = threadIdx.x;
  if (t < MLP_H)
    unsafeAtomicAdd(&gstat_out[t], ls[0][t] + ls[1][t] + ls[2][t] + ls[3][t]);
  else if (t < 2*MLP_H)
    unsafeAtomicAdd(&gstat_out[t], lq[0][t-MLP_H] + lq[1][t-MLP_H] + lq[2][t-MLP_H] + lq[3][t-MLP_H]);
}

// -------------------- update stage 2 + tu stats (BNu1 coefs inline via LDS) -----------
__global__ __launch_bounds__(TPB) void k_upd2(const float* __restrict__ zu1,
                                              const float* __restrict__ gstat_in, // zu1 stats (N count)
                                              const float* __restrict__ gu1,
                                              const float* __restrict__ beu1,
                                              const float* __restrict__ w2,
                                              const float* __restrict__ b2,
                                              float* __restrict__ tu,
                                              float* __restrict__ gstat_out) {
  __shared__ float sa[MLP_H], sc[MLP_H];
  {
    int t = threadIdx.x;
    if (t < MLP_H) {
      float mu = gstat_in[t] * (1.f / N_NODES);
      float var = fmaxf(gstat_in[MLP_H + t] * (1.f / N_NODES) - mu * mu, 0.f);
      float a = gu1[t] * rsqrtf(var + EPS);
      sa[t] = a; sc[t] = beu1[t] - a * mu;
    }
  }
  __syncthreads();
  int i = blockIdx.x * TPB + threadIdx.x;
  bool valid = i < N_NODES;
  float m1[MLP_H];
#pragma unroll
  for (int kk = 0; kk < MLP_H; ++kk) m1[kk] = 0.f;
  if (valid) {
    const float4* zp = reinterpret_cast<const float4*>(zu1 + i * MLP_H);
#pragma unroll
    for (int c = 0; c < MLP_H/4; ++c) {
      float4 z = zp[c];
      int kk = 4*c;
      m1[kk]   = fmaxf(sa[kk]  *z.x + sc[kk],   0.f);
      m1[kk+1] = fmaxf(sa[kk+1]*z.y + sc[kk+1], 0.f);
      m1[kk+2] = fmaxf(sa[kk+2]*z.z + sc[kk+2], 0.f);
      m1[kk+3] = fmaxf(sa[kk+3]*z.w + sc[kk+3], 0.f);
    }
  }
  int lane = threadIdx.x & 63;
  float ks = 0.f, kq = 0.f;
#pragma unroll 2
  for (int j4 = 0; j4 < HID/4; ++j4) {
    float tv[4];
#pragma unroll
    for (int c = 0; c < 4; ++c) {
      int j = j4*4 + c;
      float v = 0.f;
      if (valid) {
        v = b2[j];
#pragma unroll
        for (int kk = 0; kk < MLP_H; ++kk) v += m1[kk] * w2[kk*HID + j];
        v = fmaxf(v, 0.f);
      }
      tv[c] = v;
      float sv = wsum(v);
      float qv = wsum(v*v);
      if (lane == j) { ks = sv; kq = qv; }
    }
    if (valid) {
      float4 o = {tv[0], tv[1], tv[2], tv[3]};
      *reinterpret_cast<float4*>(tu + i * HID + j4*4) = o;
    }
  }
  __shared__ float ls[4][HID], lq[4][HID];
  int w = threadIdx.x >> 6;
  ls[w][lane] = ks; lq[w][lane] = kq;
  __syncthreads();
  int t = threadIdx.x;
  if (t < HID)
    unsafeAtomicAdd(&gstat_out[t], ls[0][t] + ls[1][t] + ls[2][t] + ls[3][t]);
  else if (t < 2*HID)
    unsafeAtomicAdd(&gstat_out[t], lq[0][t-HID] + lq[1][t-HID] + lq[2][t-HID] + lq[3][t-HID]);
}

// -------------------- residual (BNu2 coefs inline via LDS) --------------------
__global__ __launch_bounds__(TPB) void k_resid(float* __restrict__ h,
                                               const float* __restrict__ tu,
                                               const float* __restrict__ gstat_in, // tu stats (N count)
                                               const float* __restrict__ gu2,
                                               const float* __restrict__ beu2) {
  __shared__ float sa[HID], sc[HID];
  {
    int t = threadIdx.x;
    if (t < HID) {
      float mu = gstat_in[t] * (1.f / N_NODES);
      float var = fmaxf(gstat_in[HID + t] * (1.f / N_NODES) - mu * mu, 0.f);
      float a = gu2[t] * rsqrtf(var + EPS);
      sa[t] = a; sc[t] = beu2[t] - a * mu;
    }
  }
  __syncthreads();
  int idx = blockIdx.x * TPB + threadIdx.x;
  if (idx >= N_NODES * (HID/4)) return;
  int j0 = (idx & (HID/4 - 1)) * 4;
  float4 hv = reinterpret_cast<const float4*>(h)[idx];
  float4 tv = reinterpret_cast<const float4*>(tu)[idx];
  hv.x += sa[j0]  *tv.x + sc[j0];
  hv.y += sa[j0+1]*tv.y + sc[j0+1];
  hv.z += sa[j0+2]*tv.z + sc[j0+2];
  hv.w += sa[j0+3]*tv.w + sc[j0+3];
  reinterpret_cast<float4*>(h)[idx] = hv;
}

// -------------------- pool + head --------------------
__global__ __launch_bounds__(TPB) void k_pool_head(const float* __restrict__ h,
                                                   const int* __restrict__ batch,
                                                   const float* __restrict__ ow,
                                                   const float* __restrict__ ob,
                                                   float* __restrict__ out) {
  int g = blockIdx.x;
  int lo = 0, hi = N_NODES;
  while (lo < hi) { int mid = (lo+hi) >> 1; if (batch[mid] < g) lo = mid+1; else hi = mid; }
  int start = lo;
  lo = start; hi = N_NODES;
  while (lo < hi) { int mid = (lo+hi) >> 1; if (batch[mid] < g+1) lo = mid+1; else hi = mid; }
  int end = lo;
  int j = threadIdx.x & 63;
  int sub = threadIdx.x >> 6;
  float acc = 0.f;
  for (int n = start + sub; n < end; n += 4) acc += h[n*HID + j];
  __shared__ float red[TPB];
  red[threadIdx.x] = acc;
  __syncthreads();
  if (threadIdx.x < 64) {
    float s = red[threadIdx.x] + red[64+threadIdx.x] + red[128+threadIdx.x] + red[192+threadIdx.x];
    float cnt = (float)(end - start);
    float pooled = s / fmaxf(cnt, 1.0f);
    float v = pooled * ow[threadIdx.x];
    v = wsum(v);
    if (threadIdx.x == 0) out[g] = fmaxf(v + ob[0], 0.f);
  }
}

// -------------------- launch --------------------
extern "C" void kernel_launch(void* const* d_in, const int* in_sizes, int n_in,
                              void* d_out, int out_size, void* d_ws, size_t ws_size,
                              hipStream_t stream) {
  const float* x       = (const float*)d_in[0];
  const int*   ei      = (const int*)  d_in[1];
  const float* ea      = (const float*)d_in[2];
  const int*   batch   = (const int*)  d_in[3];
  const float* lin_w   = (const float*)d_in[4];
  const float* lin_b   = (const float*)d_in[5];
  const float* msg_w1  = (const float*)d_in[6];
  const float* msg_b1  = (const float*)d_in[7];
  const float* msg_g1  = (const float*)d_in[8];
  const float* msg_be1 = (const float*)d_in[9];
  const float* msg_w2  = (const float*)d_in[10];
  const float* msg_b2  = (const float*)d_in[11];
  const float* msg_g2  = (const float*)d_in[12];
  const float* msg_be2 = (const float*)d_in[13];
  const float* upd_w1  = (const float*)d_in[14];
  const float* upd_b1  = (const float*)d_in[15];
  const float* upd_g1  = (const float*)d_in[16];
  const float* upd_be1 = (const float*)d_in[17];
  const float* upd_w2  = (const float*)d_in[18];
  const float* upd_b2  = (const float*)d_in[19];
  const float* upd_g2  = (const float*)d_in[20];
  const float* upd_be2 = (const float*)d_in[21];
  const float* out_w   = (const float*)d_in[22];
  const float* out_b   = (const float*)d_in[23];
  float* out = (float*)d_out;

  float* W     = (float*)d_ws;
  float* h     = W;                       //  6,400,000
  float* P     = W + 6400000;             //  3,200,000
  float* Qb    = W + 9600000;             //  3,200,000
  float* agg   = W + 12800000;            //  6,400,000
  float* z1    = W + 19200000;            // 25,600,000 f32 reserve (f16 uses half)
  _Float16* z1h = (_Float16*)z1;          //  800,000 x 32 f16 = 51.2 MB
  float* zu1   = z1 + 12800000;           //  3,200,000 (after z1h's 12.8M floats)
  float* tu    = z1 + 16000000;           //  6,400,000
  float* eaS   = W + 44800000;            //    800,000
  float* stats = W + 45600000;            //  3*384
  int*   ib    = (int*)(W + 45601152);
  int* deg       = ib;                    //   100,000
  int* row_start = ib + 100000;           //   100,001
  int* cursor    = ib + 200001;           //   100,000
  int* srcS      = ib + 300001;           //   800,000
  int* dstS      = ib + 1100001;          //   800,000
  int* partials  = ib + 1900001;          //   NCHUNK

  hipMemsetAsync(stats, 0, 3*384*sizeof(float), stream);
  hipMemsetAsync(deg, 0, N_NODES*sizeof(int), stream);

  // CSR build
  k_deg<<<N_EDGES/TPB, TPB, 0, stream>>>(ei, deg);
  k_scan_part<<<NCHUNK, SCAN_B, 0, stream>>>(deg, partials);
  k_scan_mid<<<1, 1, 0, stream>>>(partials, row_start);
  k_scan_fin<<<NCHUNK, SCAN_B, 0, stream>>>(deg, partials, row_start, cursor);
  k_fill<<<N_EDGES/TPB, TPB, 0, stream>>>(ei, ea, cursor, srcS, dstS, eaS);

  k_lin_in<<<(N_NODES+TPB-1)/TPB, TPB, 0, stream>>>(x, lin_w, lin_b, h);

  const int NODE_BLKS = (N_NODES + TPB - 1) / TPB;       // 391

  for (int l = 0; l < 3; ++l) {
    const float* mw1 = msg_w1 + (size_t)l*129*MLP_H;
    const float* mb1 = msg_b1 + l*MLP_H;
    const float* mg1 = msg_g1 + l*MLP_H;
    const float* mbe1= msg_be1 + l*MLP_H;
    const float* mw2 = msg_w2 + (size_t)l*MLP_H*HID;
    const float* mb2 = msg_b2 + l*HID;
    const float* mg2 = msg_g2 + l*HID;
    const float* mbe2= msg_be2 + l*HID;
    const float* uw1 = upd_w1 + (size_t)l*128*MLP_H;
    const float* ub1 = upd_b1 + l*MLP_H;
    const float* ug1 = upd_g1 + l*MLP_H;
    const float* ube1= upd_be1 + l*MLP_H;
    const float* uw2 = upd_w2 + (size_t)l*MLP_H*HID;
    const float* ub2 = upd_b2 + l*HID;
    const float* ug2 = upd_g2 + l*HID;
    const float* ube2= upd_be2 + l*HID;
    float* st = stats + l*384;   // [0:64) BN1 | [64:192) BN2 | [192:256) BNu1 | [256:384) BNu2

    k_pq<<<NODE_BLKS, TPB, 0, stream>>>(h, mw1, mb1, P, Qb);
    k_gather<<<GSB, TPB, 0, stream>>>(P, Qb, srcS, dstS, eaS, mw1, z1h, st);
    k_msgdot<<<GSB, TPB, 0, stream>>>(z1h, row_start, st, mg1, mbe1, mw2, mb2, agg, st+64);
    k_upd1<<<NODE_BLKS, TPB, 0, stream>>>(h, agg, deg, st+64, mg2, mbe2, uw1, ub1, zu1, st+192);
    k_upd2<<<NODE_BLKS, TPB, 0, stream>>>(zu1, st+192, ug1, ube1, uw2, ub2, tu, st+256);
    k_resid<<<(N_NODES*(HID/4)+TPB-1)/TPB, TPB, 0, stream>>>(h, tu, st+256, ug2, ube2);
  }

  k_pool_head<<<NUM_GRAPHS, TPB, 0, stream>>>(h, batch, out_w, out_b, out);
}